// Round 1
// baseline (1564.455 us; speedup 1.0000x reference)
//
#include <hip/hip_runtime.h>

#define NN 50000
#define NE 10000
#define NNZ_INC 400000
#define NNZ_E 80000
#define NNZ_V 400000
#define D 128

// ---------------- dense GEMM: out[M,128] = act(X[M,128] @ W[:, off:off+128].T + b) ----
// W row-major [128, ldw]; pass W pointer pre-offset. 64 rows/block, 256 threads.
__global__ __launch_bounds__(256) void gemm128(
    const float* __restrict__ X, const float* __restrict__ W, int ldw,
    const float* __restrict__ bias, float* __restrict__ out, int M, int doRelu)
{
    __shared__ float Xs[64 * D];      // 32 KB
    __shared__ float Ws[D * 33];      // 16.9 KB, +1 pad kills bank conflicts
    const int tid = threadIdx.x;
    const int row0 = blockIdx.x * 64;

    // load X tile (64x128) as float4, coalesced
#pragma unroll
    for (int i = 0; i < 8; ++i) {
        int l = tid + i * 256;        // float4 index, 2048 total
        int r = l >> 5;               // 32 float4 per row
        int c4 = l & 31;
        float4 v = make_float4(0.f, 0.f, 0.f, 0.f);
        int row = row0 + r;
        if (row < M) v = ((const float4*)(X + (size_t)row * D))[c4];
        ((float4*)Xs)[l] = v;
    }

    const int col = tid & (D - 1);
    const int rh  = tid >> 7;         // 0/1: which interleaved row half
    float acc[32];
#pragma unroll
    for (int j = 0; j < 32; ++j) acc[j] = 0.f;

    for (int kc = 0; kc < D; kc += 32) {
        __syncthreads();              // Xs ready / prev compute done
        // stage W chunk: o=0..127, k=kc..kc+31 -> Ws[o*33 + kk]
#pragma unroll
        for (int i = 0; i < 4; ++i) {
            int l = tid + i * 256;    // 0..1023 float4
            int o = l >> 3;
            int k4 = l & 7;
            float4 w4 = ((const float4*)(W + (size_t)o * ldw + kc))[k4];
            int base = o * 33 + k4 * 4;
            Ws[base + 0] = w4.x; Ws[base + 1] = w4.y;
            Ws[base + 2] = w4.z; Ws[base + 3] = w4.w;
        }
        __syncthreads();
        for (int kq = 0; kq < 32; kq += 4) {
            float w0 = Ws[col * 33 + kq + 0];
            float w1 = Ws[col * 33 + kq + 1];
            float w2 = Ws[col * 33 + kq + 2];
            float w3 = Ws[col * 33 + kq + 3];
#pragma unroll
            for (int j = 0; j < 32; ++j) {
                const float4 x = *(const float4*)&Xs[(j * 2 + rh) * D + kc + kq];
                acc[j] = fmaf(x.w, w3, fmaf(x.z, w2, fmaf(x.y, w1, fmaf(x.x, w0, acc[j]))));
            }
        }
    }

    float b = bias ? bias[col] : 0.f;
#pragma unroll
    for (int j = 0; j < 32; ++j) {
        int row = row0 + j * 2 + rh;
        if (row < M) {
            float v = acc[j] + b;
            if (doRelu) v = fmaxf(v, 0.f);
            out[(size_t)row * D + col] = v;
        }
    }
}

// ---------------- per-incidence scalar degree sums -----------------------------------
__global__ void deg_kernel(const int* __restrict__ src, const int* __restrict__ dst,
                           const float* __restrict__ invDV,
                           float* __restrict__ wdeg, float* __restrict__ deg, int nnz)
{
    int i = blockIdx.x * 256 + threadIdx.x;
    if (i >= nnz) return;
    int d = dst[i];
    atomicAdd(wdeg + d, invDV[src[i]]);
    atomicAdd(deg + d, 1.0f);
}

// ---------------- A[dst] += invDV[src] * Pv[src] --------------------------------------
__global__ void scatter_psi1(const int* __restrict__ src, const int* __restrict__ dst,
                             const float* __restrict__ invDV, const float* __restrict__ Pv,
                             float* __restrict__ A, int nnz)
{
    int i = blockIdx.x * 2 + (threadIdx.x >> 7);
    int c = threadIdx.x & (D - 1);
    if (i >= nnz) return;
    int s = src[i], d = dst[i];
    float w = invDV[s];
    atomicAdd(A + (size_t)d * D + c, w * Pv[(size_t)s * D + c]);
}

// ---------------- finalize A, seed A2 = efeat -----------------------------------------
__global__ void finalize_A(const float* __restrict__ wdeg, const float* __restrict__ PeP,
                           const float* __restrict__ efeat,
                           float* __restrict__ A, float* __restrict__ A2, int E)
{
    int i = blockIdx.x * 256 + threadIdx.x;
    if (i >= E * D) return;
    int e = i >> 7;
    A[i] = A[i] + wdeg[e] * PeP[i];
    A2[i] = efeat[i];
}

// ---------------- COO spmm scatter: Y[rows] += vals * X[cols] -------------------------
__global__ void spmm_scatter(const int* __restrict__ rows, const int* __restrict__ cols,
                             const float* __restrict__ vals,
                             const float* __restrict__ Xin, float* __restrict__ Y, int nnz)
{
    int i = blockIdx.x * 2 + (threadIdx.x >> 7);
    int c = threadIdx.x & (D - 1);
    if (i >= nnz) return;
    int r = rows[i], cc = cols[i];
    float v = vals[i];
    atomicAdd(Y + (size_t)r * D + c, v * Xin[(size_t)cc * D + c]);
}

// ---------------- fused: _vfeat[src] += _efeat[dst]; _vfeat2[src] += efeat[dst] -------
__global__ void scatter_con(const int* __restrict__ src, const int* __restrict__ dst,
                            const float* __restrict__ ef1, const float* __restrict__ ef0,
                            float* __restrict__ vf1, float* __restrict__ vf2, int nnz)
{
    int i = blockIdx.x * 2 + (threadIdx.x >> 7);
    int c = threadIdx.x & (D - 1);
    if (i >= nnz) return;
    int s = src[i], d = dst[i];
    size_t so = (size_t)s * D + c, dof = (size_t)d * D + c;
    atomicAdd(vf1 + so, ef1[dof]);
    atomicAdd(vf2 + so, ef0[dof]);
}

// ---------------- generic: Y[dst] += X[src] -------------------------------------------
__global__ void scatter_sum(const int* __restrict__ src, const int* __restrict__ dst,
                            const float* __restrict__ Xin, float* __restrict__ Y, int nnz)
{
    int i = blockIdx.x * 2 + (threadIdx.x >> 7);
    int c = threadIdx.x & (D - 1);
    if (i >= nnz) return;
    int s = src[i], d = dst[i];
    atomicAdd(Y + (size_t)d * D + c, Xin[(size_t)s * D + c]);
}

// ---------------- _efeat2_init = (Bbuf + deg*QeP) * invDE -----------------------------
__global__ void make_B(const float* __restrict__ Bbuf, const float* __restrict__ deg,
                       const float* __restrict__ QeP, const float* __restrict__ invDE,
                       float* __restrict__ ef2, int E)
{
    int i = blockIdx.x * 256 + threadIdx.x;
    if (i >= E * D) return;
    int e = i >> 7;
    ef2[i] = (Bbuf[i] + deg[e] * QeP[i]) * invDE[e];
}

extern "C" void kernel_launch(void* const* d_in, const int* in_sizes, int n_in,
                              void* d_out, int out_size, void* d_ws, size_t ws_size,
                              hipStream_t stream)
{
    (void)in_sizes; (void)n_in; (void)out_size; (void)ws_size;
    const float* vfeat     = (const float*)d_in[0];
    const float* efeat     = (const float*)d_in[1];
    const float* invDV     = (const float*)d_in[2];
    const float* invDE     = (const float*)d_in[3];
    const int*   inc_src   = (const int*)d_in[4];
    const int*   inc_dst   = (const int*)d_in[5];
    const int*   emat_rows = (const int*)d_in[6];
    const int*   emat_cols = (const int*)d_in[7];
    const float* emat_vals = (const float*)d_in[8];
    const int*   vmat_rows = (const int*)d_in[9];
    const int*   vmat_cols = (const int*)d_in[10];
    const float* Wv        = (const float*)d_in[12];
    const float* We        = (const float*)d_in[13];
    const float* psi1_W    = (const float*)d_in[14];
    const float* psi1_b    = (const float*)d_in[15];
    const float* psi2_W    = (const float*)d_in[16];
    const float* psi2_b    = (const float*)d_in[17];
    const float* vmat_vals = (const float*)d_in[11];

    const size_t ND = (size_t)NN * D;   // 6.4M floats
    const size_t ED = (size_t)NE * D;   // 1.28M floats
    float* bufA = (float*)d_ws;         // Pv, later Qv        (GEMM fully overwrites)
    float* bufB = bufA + ND;            // _vfeat, later _vfeat2b
    float* bufC = bufB + ND;            // _vfeat2
    float* Abuf = bufC + ND;            // A  (zeroed)
    float* Bbuf = Abuf + ED;            // B scatter buf (zeroed)
    float* wdeg = Bbuf + ED;            // (zeroed)
    float* degb = wdeg + NE;            // (zeroed)
    float* A2   = degb + NE;            // _efeat
    float* PeP  = A2 + ED;
    float* QeP  = PeP + ED;
    float* ef2  = QeP + ED;             // _efeat2
    // total ~107.6 MB

    float* out_v = (float*)d_out;       // vfeat_out [NN,128]
    float* out_e = out_v + ND;          // efeat_out [NE,128]

    hipMemsetAsync(bufB, 0, 2 * ND * sizeof(float), stream);              // _vfeat,_vfeat2
    hipMemsetAsync(Abuf, 0, (2 * ED + 2 * NE) * sizeof(float), stream);   // A,Bbuf,wdeg,deg

    dim3 b256(256);
    int gN = (NN + 63) / 64, gE = (NE + 63) / 64;

    // --- psi1 path: A[e] = sum invDV[s]*Pv[s] + wdeg[e]*(Pe[e]+b1)
    gemm128<<<gN, b256, 0, stream>>>(vfeat, psi1_W, 2 * D, nullptr, bufA, NN, 0);      // Pv
    gemm128<<<gE, b256, 0, stream>>>(efeat, psi1_W + D, 2 * D, psi1_b, PeP, NE, 0);    // Pe+b
    deg_kernel<<<(NNZ_INC + 255) / 256, b256, 0, stream>>>(inc_src, inc_dst, invDV, wdeg, degb, NNZ_INC);
    scatter_psi1<<<(NNZ_INC + 1) / 2, b256, 0, stream>>>(inc_src, inc_dst, invDV, bufA, Abuf, NNZ_INC);
    finalize_A<<<(NE * D + 255) / 256, b256, 0, stream>>>(wdeg, PeP, efeat, Abuf, A2, NE);
    // _efeat = emat @ A + efeat   (A2 seeded with efeat above)
    spmm_scatter<<<(NNZ_E + 1) / 2, b256, 0, stream>>>(emat_rows, emat_cols, emat_vals, Abuf, A2, NNZ_E);
    // _vfeat = seg_sum(_efeat[dst] -> src); _vfeat2 = seg_sum(efeat[dst] -> src)
    scatter_con<<<(NNZ_INC + 1) / 2, b256, 0, stream>>>(inc_src, inc_dst, A2, efeat, bufB, bufC, NNZ_INC);
    // vfeat_out = relu(_vfeat @ Wv.T)
    gemm128<<<gN, b256, 0, stream>>>(bufB, Wv, D, nullptr, out_v, NN, 1);
    // --- psi2 path: B[e] = (sum Qv[s] + deg[e]*(Qe[e]+b2)) * invDE[e]
    gemm128<<<gN, b256, 0, stream>>>(out_v, psi2_W, 2 * D, nullptr, bufA, NN, 0);      // Qv
    gemm128<<<gE, b256, 0, stream>>>(efeat, psi2_W + D, 2 * D, psi2_b, QeP, NE, 0);    // Qe+b
    scatter_sum<<<(NNZ_INC + 1) / 2, b256, 0, stream>>>(inc_src, inc_dst, bufA, Bbuf, NNZ_INC);
    make_B<<<(NE * D + 255) / 256, b256, 0, stream>>>(Bbuf, degb, QeP, invDE, ef2, NE);
    // --- vMat path: _efeat2 = seg_sum((vMat @ _vfeat2)[src] -> dst) + B
    hipMemsetAsync(bufB, 0, ND * sizeof(float), stream);                                // _vfeat2b
    spmm_scatter<<<(NNZ_V + 1) / 2, b256, 0, stream>>>(vmat_rows, vmat_cols, vmat_vals, bufC, bufB, NNZ_V);
    scatter_sum<<<(NNZ_INC + 1) / 2, b256, 0, stream>>>(inc_src, inc_dst, bufB, ef2, NNZ_INC);
    // efeat_out = relu(_efeat2 @ We.T)
    gemm128<<<gE, b256, 0, stream>>>(ef2, We, D, nullptr, out_e, NE, 1);
}

// Round 2
// 1049.737 us; speedup vs baseline: 1.4903x; 1.4903x over previous
//
#include <hip/hip_runtime.h>

#define NN 50000
#define NE 10000
#define NNZ_INC 400000
#define NNZ_E 80000
#define NNZ_V 400000
#define D 128

// ---------------- dense GEMM: out[M,128] = act(X[M,128] @ W[:, off:off+128].T + b) ----
__global__ __launch_bounds__(256) void gemm128(
    const float* __restrict__ X, const float* __restrict__ W, int ldw,
    const float* __restrict__ bias, float* __restrict__ out, int M, int doRelu)
{
    __shared__ float Xs[64 * D];
    __shared__ float Ws[D * 33];
    const int tid = threadIdx.x;
    const int row0 = blockIdx.x * 64;

#pragma unroll
    for (int i = 0; i < 8; ++i) {
        int l = tid + i * 256;
        int r = l >> 5;
        int c4 = l & 31;
        float4 v = make_float4(0.f, 0.f, 0.f, 0.f);
        int row = row0 + r;
        if (row < M) v = ((const float4*)(X + (size_t)row * D))[c4];
        ((float4*)Xs)[l] = v;
    }

    const int col = tid & (D - 1);
    const int rh  = tid >> 7;
    float acc[32];
#pragma unroll
    for (int j = 0; j < 32; ++j) acc[j] = 0.f;

    for (int kc = 0; kc < D; kc += 32) {
        __syncthreads();
#pragma unroll
        for (int i = 0; i < 4; ++i) {
            int l = tid + i * 256;
            int o = l >> 3;
            int k4 = l & 7;
            float4 w4 = ((const float4*)(W + (size_t)o * ldw + kc))[k4];
            int base = o * 33 + k4 * 4;
            Ws[base + 0] = w4.x; Ws[base + 1] = w4.y;
            Ws[base + 2] = w4.z; Ws[base + 3] = w4.w;
        }
        __syncthreads();
        for (int kq = 0; kq < 32; kq += 4) {
            float w0 = Ws[col * 33 + kq + 0];
            float w1 = Ws[col * 33 + kq + 1];
            float w2 = Ws[col * 33 + kq + 2];
            float w3 = Ws[col * 33 + kq + 3];
#pragma unroll
            for (int j = 0; j < 32; ++j) {
                const float4 x = *(const float4*)&Xs[(j * 2 + rh) * D + kc + kq];
                acc[j] = fmaf(x.w, w3, fmaf(x.z, w2, fmaf(x.y, w1, fmaf(x.x, w0, acc[j]))));
            }
        }
    }

    float b = bias ? bias[col] : 0.f;
#pragma unroll
    for (int j = 0; j < 32; ++j) {
        int row = row0 + j * 2 + rh;
        if (row < M) {
            float v = acc[j] + b;
            if (doRelu) v = fmaxf(v, 0.f);
            out[(size_t)row * D + col] = v;
        }
    }
}

// ---------------- CSR build: histograms ----------------------------------------------
__global__ void hist_inc(const int* __restrict__ src, const int* __restrict__ dst,
                         int* __restrict__ cnt_src, int* __restrict__ cnt_dst, int nnz)
{
    int i = blockIdx.x * 256 + threadIdx.x;
    if (i >= nnz) return;
    atomicAdd(cnt_dst + dst[i], 1);
    atomicAdd(cnt_src + src[i], 1);
}

__global__ void hist_key(const int* __restrict__ keys, int* __restrict__ cnt, int nnz)
{
    int i = blockIdx.x * 256 + threadIdx.x;
    if (i >= nnz) return;
    atomicAdd(cnt + keys[i], 1);
}

// ---------------- single-block exclusive scan (256 thr, 8 elems/thr/chunk) ------------
__global__ void exscan_kernel(const int* __restrict__ counts, int* __restrict__ offs,
                              int* __restrict__ cursor, int n)
{
    __shared__ int wsum[4];
    __shared__ int carry_s;
    int lane = threadIdx.x & 63, wid = threadIdx.x >> 6;
    if (threadIdx.x == 0) carry_s = 0;
    __syncthreads();
    for (int base = 0; base < n; base += 2048) {
        int i0 = base + threadIdx.x * 8;
        int v[8]; int tsum = 0;
#pragma unroll
        for (int k = 0; k < 8; ++k) {
            int i = i0 + k;
            v[k] = (i < n) ? counts[i] : 0;
            tsum += v[k];
        }
        int incl = tsum;
#pragma unroll
        for (int s = 1; s < 64; s <<= 1) {
            int t = __shfl_up(incl, s, 64);
            if (lane >= s) incl += t;
        }
        if (lane == 63) wsum[wid] = incl;
        __syncthreads();
        int woff = 0;
        for (int w = 0; w < wid; ++w) woff += wsum[w];
        int carry = carry_s;
        int run = incl - tsum + woff + carry;
#pragma unroll
        for (int k = 0; k < 8; ++k) {
            int i = i0 + k;
            if (i < n) { offs[i] = run; cursor[i] = run; }
            run += v[k];
        }
        __syncthreads();
        if (threadIdx.x == 255)
            carry_s = carry + wsum[0] + wsum[1] + wsum[2] + wsum[3];
        __syncthreads();
    }
    if (threadIdx.x == 0) offs[n] = carry_s;
}

// ---------------- CSR build: fills ----------------------------------------------------
__global__ void fill_inc(const int* __restrict__ src, const int* __restrict__ dst,
                         int* __restrict__ cur_dst, int* __restrict__ srcs_s,
                         int* __restrict__ cur_src, int* __restrict__ dsts_s, int nnz)
{
    int i = blockIdx.x * 256 + threadIdx.x;
    if (i >= nnz) return;
    int s = src[i], d = dst[i];
    srcs_s[atomicAdd(cur_dst + d, 1)] = s;
    dsts_s[atomicAdd(cur_src + s, 1)] = d;
}

__global__ void fill_coo(const int* __restrict__ rows, const int* __restrict__ cols,
                         const float* __restrict__ vals, int* __restrict__ cur,
                         int* __restrict__ cols_s, float* __restrict__ vals_s, int nnz)
{
    int i = blockIdx.x * 256 + threadIdx.x;
    if (i >= nnz) return;
    int p = atomicAdd(cur + rows[i], 1);
    cols_s[p] = cols[i];
    vals_s[p] = vals[i];
}

// ---------------- A[e,:] = sum_s invDV[s]*Pv[s,:] + (sum_s invDV[s])*PeP[e,:] --------
__global__ __launch_bounds__(256) void gather_A(
    const int* __restrict__ offs, const int* __restrict__ srcs,
    const float* __restrict__ invDV, const float* __restrict__ Pv,
    const float* __restrict__ PeP, float* __restrict__ A, int E)
{
    int e = blockIdx.x * 4 + (threadIdx.x >> 6);
    int l = threadIdx.x & 63;
    if (e >= E) return;
    int j0 = offs[e], j1 = offs[e + 1];
    float2 acc = make_float2(0.f, 0.f);
    float wsum = 0.f;
    for (int j = j0; j < j1; ++j) {
        int s = srcs[j];
        float w = invDV[s];
        float2 p = ((const float2*)(Pv + (size_t)s * D))[l];
        wsum += w;
        acc.x = fmaf(w, p.x, acc.x);
        acc.y = fmaf(w, p.y, acc.y);
    }
    float2 pe = ((const float2*)(PeP + (size_t)e * D))[l];
    acc.x = fmaf(wsum, pe.x, acc.x);
    acc.y = fmaf(wsum, pe.y, acc.y);
    ((float2*)(A + (size_t)e * D))[l] = acc;
}

// ---------------- Y[r,:] = (addend?addend[r,:]:0) + sum_j vals_j * X[cols_j,:] -------
__global__ __launch_bounds__(256) void gather_spmm(
    const int* __restrict__ offs, const int* __restrict__ cols,
    const float* __restrict__ vals, const float* __restrict__ X,
    const float* __restrict__ addend, float* __restrict__ Y, int R)
{
    int r = blockIdx.x * 4 + (threadIdx.x >> 6);
    int l = threadIdx.x & 63;
    if (r >= R) return;
    int j0 = offs[r], j1 = offs[r + 1];
    float2 acc = addend ? ((const float2*)(addend + (size_t)r * D))[l]
                        : make_float2(0.f, 0.f);
    for (int j = j0; j < j1; ++j) {
        int c = cols[j];
        float v = vals[j];
        float2 x = ((const float2*)(X + (size_t)c * D))[l];
        acc.x = fmaf(v, x.x, acc.x);
        acc.y = fmaf(v, x.y, acc.y);
    }
    ((float2*)(Y + (size_t)r * D))[l] = acc;
}

// ---------------- vf1[n,:] = sum_d ef1[d,:]; vf2[n,:] = sum_d ef0[d,:] ---------------
__global__ __launch_bounds__(256) void gather_src2(
    const int* __restrict__ offs, const int* __restrict__ dsts,
    const float* __restrict__ ef1, const float* __restrict__ ef0,
    float* __restrict__ vf1, float* __restrict__ vf2, int N)
{
    int n = blockIdx.x * 4 + (threadIdx.x >> 6);
    int l = threadIdx.x & 63;
    if (n >= N) return;
    int j0 = offs[n], j1 = offs[n + 1];
    float2 a1 = make_float2(0.f, 0.f), a2 = make_float2(0.f, 0.f);
    for (int j = j0; j < j1; ++j) {
        int d = dsts[j];
        float2 x1 = ((const float2*)(ef1 + (size_t)d * D))[l];
        float2 x0 = ((const float2*)(ef0 + (size_t)d * D))[l];
        a1.x += x1.x; a1.y += x1.y;
        a2.x += x0.x; a2.y += x0.y;
    }
    ((float2*)(vf1 + (size_t)n * D))[l] = a1;
    ((float2*)(vf2 + (size_t)n * D))[l] = a2;
}

// ------- ef2[e,:] = (sum_s Qv[s,:] + deg[e]*QeP[e,:]) * invDE[e] + sum_s vf2b[s,:] ---
__global__ __launch_bounds__(256) void gather_final(
    const int* __restrict__ offs, const int* __restrict__ srcs,
    const float* __restrict__ Qv, const float* __restrict__ QeP,
    const float* __restrict__ invDE, const float* __restrict__ vf2b,
    float* __restrict__ ef2, int E)
{
    int e = blockIdx.x * 4 + (threadIdx.x >> 6);
    int l = threadIdx.x & 63;
    if (e >= E) return;
    int j0 = offs[e], j1 = offs[e + 1];
    float deg = (float)(j1 - j0);
    float2 aq = make_float2(0.f, 0.f), av = make_float2(0.f, 0.f);
    for (int j = j0; j < j1; ++j) {
        int s = srcs[j];
        float2 q = ((const float2*)(Qv + (size_t)s * D))[l];
        float2 v = ((const float2*)(vf2b + (size_t)s * D))[l];
        aq.x += q.x; aq.y += q.y;
        av.x += v.x; av.y += v.y;
    }
    float2 qe = ((const float2*)(QeP + (size_t)e * D))[l];
    float ide = invDE[e];
    float2 out;
    out.x = fmaf(deg, qe.x, aq.x) * ide + av.x;
    out.y = fmaf(deg, qe.y, aq.y) * ide + av.y;
    ((float2*)(ef2 + (size_t)e * D))[l] = out;
}

extern "C" void kernel_launch(void* const* d_in, const int* in_sizes, int n_in,
                              void* d_out, int out_size, void* d_ws, size_t ws_size,
                              hipStream_t stream)
{
    (void)in_sizes; (void)n_in; (void)out_size; (void)ws_size;
    const float* vfeat     = (const float*)d_in[0];
    const float* efeat     = (const float*)d_in[1];
    const float* invDV     = (const float*)d_in[2];
    const float* invDE     = (const float*)d_in[3];
    const int*   inc_src   = (const int*)d_in[4];
    const int*   inc_dst   = (const int*)d_in[5];
    const int*   emat_rows = (const int*)d_in[6];
    const int*   emat_cols = (const int*)d_in[7];
    const float* emat_vals = (const float*)d_in[8];
    const int*   vmat_rows = (const int*)d_in[9];
    const int*   vmat_cols = (const int*)d_in[10];
    const float* vmat_vals = (const float*)d_in[11];
    const float* Wv        = (const float*)d_in[12];
    const float* We        = (const float*)d_in[13];
    const float* psi1_W    = (const float*)d_in[14];
    const float* psi1_b    = (const float*)d_in[15];
    const float* psi2_W    = (const float*)d_in[16];
    const float* psi2_b    = (const float*)d_in[17];

    const size_t ND = (size_t)NN * D;
    const size_t ED = (size_t)NE * D;

    // float buffers (reused across phases)
    float* F0 = (float*)d_ws;    // Pv -> Qv           [NN,D]
    float* F1 = F0 + ND;         // vf1 -> vf2b        [NN,D]
    float* F2 = F1 + ND;         // vf2                [NN,D]
    float* F3 = F2 + ND;         // PeP -> QeP         [NE,D]
    float* F4 = F3 + ED;         // A  -> ef2          [NE,D]
    float* F5 = F4 + ED;         // A2 (_efeat)        [NE,D]

    // int/CSR region
    int* ip       = (int*)(F5 + ED);
    int* cnt_dst  = ip;  ip += NE;       // contiguous counts block for one memset
    int* cnt_src  = ip;  ip += NN;
    int* cnt_e    = ip;  ip += NE;
    int* cnt_v    = ip;  ip += NN;
    int* offs_dst = ip;  ip += NE + 1;
    int* cur_dst  = ip;  ip += NE;
    int* srcs_s   = ip;  ip += NNZ_INC;
    int* offs_src = ip;  ip += NN + 1;
    int* cur_src  = ip;  ip += NN;
    int* dsts_s   = ip;  ip += NNZ_INC;
    int* offs_e   = ip;  ip += NE + 1;
    int* cur_e    = ip;  ip += NE;
    int* cols_e   = ip;  ip += NNZ_E;
    float* vals_e = (float*)ip; ip += NNZ_E;
    int* offs_v   = ip;  ip += NN + 1;
    int* cur_v    = ip;  ip += NN;
    int* cols_v   = ip;  ip += NNZ_V;
    float* vals_v = (float*)ip; ip += NNZ_V;

    float* out_v = (float*)d_out;     // [NN,D]
    float* out_e = out_v + ND;        // [NE,D]

    dim3 b256(256);
    int gN  = (NN + 63) / 64, gE = (NE + 63) / 64;
    int gNr = (NN + 3) / 4,  gEr = (NE + 3) / 4;   // gather grids (4 rows/block)

    // ---- CSR build ----
    hipMemsetAsync(cnt_dst, 0, (size_t)(2 * NE + 2 * NN) * sizeof(int), stream);
    hist_inc<<<(NNZ_INC + 255) / 256, b256, 0, stream>>>(inc_src, inc_dst, cnt_src, cnt_dst, NNZ_INC);
    hist_key<<<(NNZ_E + 255) / 256, b256, 0, stream>>>(emat_rows, cnt_e, NNZ_E);
    hist_key<<<(NNZ_V + 255) / 256, b256, 0, stream>>>(vmat_rows, cnt_v, NNZ_V);
    exscan_kernel<<<1, b256, 0, stream>>>(cnt_dst, offs_dst, cur_dst, NE);
    exscan_kernel<<<1, b256, 0, stream>>>(cnt_src, offs_src, cur_src, NN);
    exscan_kernel<<<1, b256, 0, stream>>>(cnt_e, offs_e, cur_e, NE);
    exscan_kernel<<<1, b256, 0, stream>>>(cnt_v, offs_v, cur_v, NN);
    fill_inc<<<(NNZ_INC + 255) / 256, b256, 0, stream>>>(inc_src, inc_dst, cur_dst, srcs_s, cur_src, dsts_s, NNZ_INC);
    fill_coo<<<(NNZ_E + 255) / 256, b256, 0, stream>>>(emat_rows, emat_cols, emat_vals, cur_e, cols_e, vals_e, NNZ_E);
    fill_coo<<<(NNZ_V + 255) / 256, b256, 0, stream>>>(vmat_rows, vmat_cols, vmat_vals, cur_v, cols_v, vals_v, NNZ_V);

    // ---- psi1 path ----
    gemm128<<<gN, b256, 0, stream>>>(vfeat, psi1_W, 2 * D, nullptr, F0, NN, 0);       // Pv
    gemm128<<<gE, b256, 0, stream>>>(efeat, psi1_W + D, 2 * D, psi1_b, F3, NE, 0);    // PeP = Pe + b1
    gather_A<<<gEr, b256, 0, stream>>>(offs_dst, srcs_s, invDV, F0, F3, F4, NE);      // A
    gather_spmm<<<gEr, b256, 0, stream>>>(offs_e, cols_e, vals_e, F4, efeat, F5, NE); // A2 = emat@A + efeat
    gather_src2<<<gNr, b256, 0, stream>>>(offs_src, dsts_s, F5, efeat, F1, F2, NN);   // vf1, vf2
    gemm128<<<gN, b256, 0, stream>>>(F1, Wv, D, nullptr, out_v, NN, 1);               // vfeat_out

    // ---- psi2 + vMat path ----
    gemm128<<<gN, b256, 0, stream>>>(out_v, psi2_W, 2 * D, nullptr, F0, NN, 0);       // Qv
    gemm128<<<gE, b256, 0, stream>>>(efeat, psi2_W + D, 2 * D, psi2_b, F3, NE, 0);    // QeP = Qe + b2
    gather_spmm<<<gNr, b256, 0, stream>>>(offs_v, cols_v, vals_v, F2, nullptr, F1, NN); // vf2b = vmat@vf2
    gather_final<<<gEr, b256, 0, stream>>>(offs_dst, srcs_s, F0, F3, invDE, F1, F4, NE); // ef2
    gemm128<<<gE, b256, 0, stream>>>(F4, We, D, nullptr, out_e, NE, 1);               // efeat_out
}

// Round 3
// 731.356 us; speedup vs baseline: 2.1391x; 1.4353x over previous
//
#include <hip/hip_runtime.h>

#define NN 50000
#define NE 10000
#define NNZ_INC 400000
#define NNZ_E 80000
#define NNZ_V 400000
#define D 128
#define KC 32

// ---------------- dense GEMM: out[M,128] = act(X[M,128] @ W[:,0:128].T + b) ----------
// Register-tiled outer product: 256 thr, 64x128 tile, each thread 8 rows x 4 cols.
__global__ __launch_bounds__(256) void gemm128(
    const float* __restrict__ X, const float* __restrict__ W, int ldw,
    const float* __restrict__ bias, float* __restrict__ out, int M, int doRelu)
{
    __shared__ float XsT[KC][68];    // [k][row], pad 68: conflict-free writes, aligned reads
    __shared__ float Ws[KC][132];    // [k][col], pad 132
    const int tid = threadIdx.x;
    const int tx = tid & 31, ty = tid >> 5;
    const int row0 = blockIdx.x * 64;
    const int c0 = tx * 4;           // 4 contiguous cols
    const int r0 = ty * 8;           // 8 contiguous rows

    float acc[8][4];
#pragma unroll
    for (int r = 0; r < 8; ++r)
#pragma unroll
        for (int c = 0; c < 4; ++c) acc[r][c] = 0.f;

    for (int kc = 0; kc < D; kc += KC) {
        __syncthreads();
        // stage X chunk 64 rows x 32 k  (2 float4 / thread), transposed into XsT
#pragma unroll
        for (int it = 0; it < 2; ++it) {
            int l = tid + it * 256;          // 0..511
            int r = l >> 3, k4 = l & 7;
            float4 v = make_float4(0.f, 0.f, 0.f, 0.f);
            int row = row0 + r;
            if (row < M) v = ((const float4*)(X + (size_t)row * D + kc))[k4];
            int k = k4 * 4;
            XsT[k + 0][r] = v.x; XsT[k + 1][r] = v.y;
            XsT[k + 2][r] = v.z; XsT[k + 3][r] = v.w;
        }
        // stage W chunk 128 out x 32 k (4 float4 / thread), transposed into Ws
#pragma unroll
        for (int it = 0; it < 4; ++it) {
            int l = tid + it * 256;          // 0..1023
            int o = l >> 3, k4 = l & 7;
            float4 w = ((const float4*)(W + (size_t)o * ldw + kc))[k4];
            int k = k4 * 4;
            Ws[k + 0][o] = w.x; Ws[k + 1][o] = w.y;
            Ws[k + 2][o] = w.z; Ws[k + 3][o] = w.w;
        }
        __syncthreads();
#pragma unroll
        for (int k = 0; k < KC; ++k) {
            const float4 a0 = *(const float4*)&XsT[k][r0];
            const float4 a1 = *(const float4*)&XsT[k][r0 + 4];
            const float4 b  = *(const float4*)&Ws[k][c0];
            float av[8] = {a0.x, a0.y, a0.z, a0.w, a1.x, a1.y, a1.z, a1.w};
            float bv[4] = {b.x, b.y, b.z, b.w};
#pragma unroll
            for (int r = 0; r < 8; ++r)
#pragma unroll
                for (int c = 0; c < 4; ++c)
                    acc[r][c] = fmaf(av[r], bv[c], acc[r][c]);
        }
    }

    float4 b4 = bias ? ((const float4*)bias)[tx] : make_float4(0.f, 0.f, 0.f, 0.f);
#pragma unroll
    for (int r = 0; r < 8; ++r) {
        int row = row0 + r0 + r;
        if (row < M) {
            float4 v;
            v.x = acc[r][0] + b4.x; v.y = acc[r][1] + b4.y;
            v.z = acc[r][2] + b4.z; v.w = acc[r][3] + b4.w;
            if (doRelu) {
                v.x = fmaxf(v.x, 0.f); v.y = fmaxf(v.y, 0.f);
                v.z = fmaxf(v.z, 0.f); v.w = fmaxf(v.w, 0.f);
            }
            ((float4*)(out + (size_t)row * D))[tx] = v;
        }
    }
}

// ---------------- CSR build: histograms ----------------------------------------------
__global__ void hist_inc(const int* __restrict__ src, const int* __restrict__ dst,
                         int* __restrict__ cnt_src, int* __restrict__ cnt_dst, int nnz)
{
    int i = blockIdx.x * 256 + threadIdx.x;
    if (i >= nnz) return;
    atomicAdd(cnt_dst + dst[i], 1);
    atomicAdd(cnt_src + src[i], 1);
}

__global__ void hist_key(const int* __restrict__ keys, int* __restrict__ cnt, int nnz)
{
    int i = blockIdx.x * 256 + threadIdx.x;
    if (i >= nnz) return;
    atomicAdd(cnt + keys[i], 1);
}

// ---------------- single-block exclusive scan (device body) ---------------------------
__device__ void exscan_block(const int* __restrict__ counts, int* __restrict__ offs,
                             int* __restrict__ cursor, int n)
{
    __shared__ int wsum[4];
    __shared__ int carry_s;
    int lane = threadIdx.x & 63, wid = threadIdx.x >> 6;
    if (threadIdx.x == 0) carry_s = 0;
    __syncthreads();
    for (int base = 0; base < n; base += 2048) {
        int i0 = base + threadIdx.x * 8;
        int v[8]; int tsum = 0;
#pragma unroll
        for (int k = 0; k < 8; ++k) {
            int i = i0 + k;
            v[k] = (i < n) ? counts[i] : 0;
            tsum += v[k];
        }
        int incl = tsum;
#pragma unroll
        for (int s = 1; s < 64; s <<= 1) {
            int t = __shfl_up(incl, s, 64);
            if (lane >= s) incl += t;
        }
        if (lane == 63) wsum[wid] = incl;
        __syncthreads();
        int woff = 0;
        for (int w = 0; w < wid; ++w) woff += wsum[w];
        int carry = carry_s;
        int run = incl - tsum + woff + carry;
#pragma unroll
        for (int k = 0; k < 8; ++k) {
            int i = i0 + k;
            if (i < n) { offs[i] = run; cursor[i] = run; }
            run += v[k];
        }
        __syncthreads();
        if (threadIdx.x == 255)
            carry_s = carry + wsum[0] + wsum[1] + wsum[2] + wsum[3];
        __syncthreads();
    }
    if (threadIdx.x == 0) offs[n] = carry_s;
}

// 4 independent scans in one launch (block per scan)
__global__ __launch_bounds__(256) void exscan4(
    const int* c0, int* o0, int* u0, int n0,
    const int* c1, int* o1, int* u1, int n1,
    const int* c2, int* o2, int* u2, int n2,
    const int* c3, int* o3, int* u3, int n3)
{
    switch (blockIdx.x) {
        case 0: exscan_block(c0, o0, u0, n0); break;
        case 1: exscan_block(c1, o1, u1, n1); break;
        case 2: exscan_block(c2, o2, u2, n2); break;
        default: exscan_block(c3, o3, u3, n3); break;
    }
}

// ---------------- CSR build: fills ----------------------------------------------------
__global__ void fill_inc(const int* __restrict__ src, const int* __restrict__ dst,
                         int* __restrict__ cur_dst, int* __restrict__ srcs_s,
                         int* __restrict__ cur_src, int* __restrict__ dsts_s, int nnz)
{
    int i = blockIdx.x * 256 + threadIdx.x;
    if (i >= nnz) return;
    int s = src[i], d = dst[i];
    srcs_s[atomicAdd(cur_dst + d, 1)] = s;
    dsts_s[atomicAdd(cur_src + s, 1)] = d;
}

__global__ void fill_coo(const int* __restrict__ rows, const int* __restrict__ cols,
                         const float* __restrict__ vals, int* __restrict__ cur,
                         int* __restrict__ cols_s, float* __restrict__ vals_s, int nnz)
{
    int i = blockIdx.x * 256 + threadIdx.x;
    if (i >= nnz) return;
    int p = atomicAdd(cur + rows[i], 1);
    cols_s[p] = cols[i];
    vals_s[p] = vals[i];
}

// ---------------- A[e,:] = sum_s invDV[s]*Pv[s,:] + (sum_s invDV[s])*PeP[e,:] --------
__global__ __launch_bounds__(256) void gather_A(
    const int* __restrict__ offs, const int* __restrict__ srcs,
    const float* __restrict__ invDV, const float* __restrict__ Pv,
    const float* __restrict__ PeP, float* __restrict__ A, int E)
{
    int e = blockIdx.x * 4 + (threadIdx.x >> 6);
    int l = threadIdx.x & 63;
    if (e >= E) return;
    int j0 = offs[e], j1 = offs[e + 1];
    float2 acc = make_float2(0.f, 0.f);
    float wsum = 0.f;
    for (int j = j0; j < j1; ++j) {
        int s = srcs[j];
        float w = invDV[s];
        float2 p = ((const float2*)(Pv + (size_t)s * D))[l];
        wsum += w;
        acc.x = fmaf(w, p.x, acc.x);
        acc.y = fmaf(w, p.y, acc.y);
    }
    float2 pe = ((const float2*)(PeP + (size_t)e * D))[l];
    acc.x = fmaf(wsum, pe.x, acc.x);
    acc.y = fmaf(wsum, pe.y, acc.y);
    ((float2*)(A + (size_t)e * D))[l] = acc;
}

// ---------------- Y[r,:] = (addend?addend[r,:]:0) + sum_j vals_j * X[cols_j,:] -------
__global__ __launch_bounds__(256) void gather_spmm(
    const int* __restrict__ offs, const int* __restrict__ cols,
    const float* __restrict__ vals, const float* __restrict__ X,
    const float* __restrict__ addend, float* __restrict__ Y, int R)
{
    int r = blockIdx.x * 4 + (threadIdx.x >> 6);
    int l = threadIdx.x & 63;
    if (r >= R) return;
    int j0 = offs[r], j1 = offs[r + 1];
    float2 acc = addend ? ((const float2*)(addend + (size_t)r * D))[l]
                        : make_float2(0.f, 0.f);
    for (int j = j0; j < j1; ++j) {
        int c = cols[j];
        float v = vals[j];
        float2 x = ((const float2*)(X + (size_t)c * D))[l];
        acc.x = fmaf(v, x.x, acc.x);
        acc.y = fmaf(v, x.y, acc.y);
    }
    ((float2*)(Y + (size_t)r * D))[l] = acc;
}

// ---------------- vf1[n,:] = sum_d ef1[d,:]; vf2[n,:] = sum_d ef0[d,:] ---------------
__global__ __launch_bounds__(256) void gather_src2(
    const int* __restrict__ offs, const int* __restrict__ dsts,
    const float* __restrict__ ef1, const float* __restrict__ ef0,
    float* __restrict__ vf1, float* __restrict__ vf2, int N)
{
    int n = blockIdx.x * 4 + (threadIdx.x >> 6);
    int l = threadIdx.x & 63;
    if (n >= N) return;
    int j0 = offs[n], j1 = offs[n + 1];
    float2 a1 = make_float2(0.f, 0.f), a2 = make_float2(0.f, 0.f);
    for (int j = j0; j < j1; ++j) {
        int d = dsts[j];
        float2 x1 = ((const float2*)(ef1 + (size_t)d * D))[l];
        float2 x0 = ((const float2*)(ef0 + (size_t)d * D))[l];
        a1.x += x1.x; a1.y += x1.y;
        a2.x += x0.x; a2.y += x0.y;
    }
    ((float2*)(vf1 + (size_t)n * D))[l] = a1;
    ((float2*)(vf2 + (size_t)n * D))[l] = a2;
}

// ------- ef2[e,:] = (sum_s Qv[s,:] + deg[e]*QeP[e,:]) * invDE[e] + sum_s vf2b[s,:] ---
__global__ __launch_bounds__(256) void gather_final(
    const int* __restrict__ offs, const int* __restrict__ srcs,
    const float* __restrict__ Qv, const float* __restrict__ QeP,
    const float* __restrict__ invDE, const float* __restrict__ vf2b,
    float* __restrict__ ef2, int E)
{
    int e = blockIdx.x * 4 + (threadIdx.x >> 6);
    int l = threadIdx.x & 63;
    if (e >= E) return;
    int j0 = offs[e], j1 = offs[e + 1];
    float deg = (float)(j1 - j0);
    float2 aq = make_float2(0.f, 0.f), av = make_float2(0.f, 0.f);
    for (int j = j0; j < j1; ++j) {
        int s = srcs[j];
        float2 q = ((const float2*)(Qv + (size_t)s * D))[l];
        float2 v = ((const float2*)(vf2b + (size_t)s * D))[l];
        aq.x += q.x; aq.y += q.y;
        av.x += v.x; av.y += v.y;
    }
    float2 qe = ((const float2*)(QeP + (size_t)e * D))[l];
    float ide = invDE[e];
    float2 out;
    out.x = fmaf(deg, qe.x, aq.x) * ide + av.x;
    out.y = fmaf(deg, qe.y, aq.y) * ide + av.y;
    ((float2*)(ef2 + (size_t)e * D))[l] = out;
}

extern "C" void kernel_launch(void* const* d_in, const int* in_sizes, int n_in,
                              void* d_out, int out_size, void* d_ws, size_t ws_size,
                              hipStream_t stream)
{
    (void)in_sizes; (void)n_in; (void)out_size; (void)ws_size;
    const float* vfeat     = (const float*)d_in[0];
    const float* efeat     = (const float*)d_in[1];
    const float* invDV     = (const float*)d_in[2];
    const float* invDE     = (const float*)d_in[3];
    const int*   inc_src   = (const int*)d_in[4];
    const int*   inc_dst   = (const int*)d_in[5];
    const int*   emat_rows = (const int*)d_in[6];
    const int*   emat_cols = (const int*)d_in[7];
    const float* emat_vals = (const float*)d_in[8];
    const int*   vmat_rows = (const int*)d_in[9];
    const int*   vmat_cols = (const int*)d_in[10];
    const float* vmat_vals = (const float*)d_in[11];
    const float* Wv        = (const float*)d_in[12];
    const float* We        = (const float*)d_in[13];
    const float* psi1_W    = (const float*)d_in[14];
    const float* psi1_b    = (const float*)d_in[15];
    const float* psi2_W    = (const float*)d_in[16];
    const float* psi2_b    = (const float*)d_in[17];

    const size_t ND = (size_t)NN * D;
    const size_t ED = (size_t)NE * D;

    float* F0 = (float*)d_ws;    // Pv -> Qv           [NN,D]
    float* F1 = F0 + ND;         // vf1 -> vf2b        [NN,D]
    float* F2 = F1 + ND;         // vf2                [NN,D]
    float* F3 = F2 + ND;         // PeP -> QeP         [NE,D]
    float* F4 = F3 + ED;         // A  -> ef2          [NE,D]
    float* F5 = F4 + ED;         // A2 (_efeat)        [NE,D]

    int* ip       = (int*)(F5 + ED);
    int* cnt_dst  = ip;  ip += NE;
    int* cnt_src  = ip;  ip += NN;
    int* cnt_e    = ip;  ip += NE;
    int* cnt_v    = ip;  ip += NN;
    int* offs_dst = ip;  ip += NE + 1;
    int* cur_dst  = ip;  ip += NE;
    int* srcs_s   = ip;  ip += NNZ_INC;
    int* offs_src = ip;  ip += NN + 1;
    int* cur_src  = ip;  ip += NN;
    int* dsts_s   = ip;  ip += NNZ_INC;
    int* offs_e   = ip;  ip += NE + 1;
    int* cur_e    = ip;  ip += NE;
    int* cols_e   = ip;  ip += NNZ_E;
    float* vals_e = (float*)ip; ip += NNZ_E;
    int* offs_v   = ip;  ip += NN + 1;
    int* cur_v    = ip;  ip += NN;
    int* cols_v   = ip;  ip += NNZ_V;
    float* vals_v = (float*)ip; ip += NNZ_V;

    float* out_v = (float*)d_out;     // [NN,D]
    float* out_e = out_v + ND;        // [NE,D]

    dim3 b256(256);
    int gN  = (NN + 63) / 64, gE = (NE + 63) / 64;
    int gNr = (NN + 3) / 4,  gEr = (NE + 3) / 4;

    // ---- CSR build ----
    hipMemsetAsync(cnt_dst, 0, (size_t)(2 * NE + 2 * NN) * sizeof(int), stream);
    hist_inc<<<(NNZ_INC + 255) / 256, b256, 0, stream>>>(inc_src, inc_dst, cnt_src, cnt_dst, NNZ_INC);
    hist_key<<<(NNZ_E + 255) / 256, b256, 0, stream>>>(emat_rows, cnt_e, NNZ_E);
    hist_key<<<(NNZ_V + 255) / 256, b256, 0, stream>>>(vmat_rows, cnt_v, NNZ_V);
    exscan4<<<4, b256, 0, stream>>>(cnt_dst, offs_dst, cur_dst, NE,
                                    cnt_src, offs_src, cur_src, NN,
                                    cnt_e,   offs_e,   cur_e,   NE,
                                    cnt_v,   offs_v,   cur_v,   NN);
    fill_inc<<<(NNZ_INC + 255) / 256, b256, 0, stream>>>(inc_src, inc_dst, cur_dst, srcs_s, cur_src, dsts_s, NNZ_INC);
    fill_coo<<<(NNZ_E + 255) / 256, b256, 0, stream>>>(emat_rows, emat_cols, emat_vals, cur_e, cols_e, vals_e, NNZ_E);
    fill_coo<<<(NNZ_V + 255) / 256, b256, 0, stream>>>(vmat_rows, vmat_cols, vmat_vals, cur_v, cols_v, vals_v, NNZ_V);

    // ---- psi1 path ----
    gemm128<<<gN, b256, 0, stream>>>(vfeat, psi1_W, 2 * D, nullptr, F0, NN, 0);       // Pv
    gemm128<<<gE, b256, 0, stream>>>(efeat, psi1_W + D, 2 * D, psi1_b, F3, NE, 0);    // PeP = Pe + b1
    gather_A<<<gEr, b256, 0, stream>>>(offs_dst, srcs_s, invDV, F0, F3, F4, NE);      // A
    gather_spmm<<<gEr, b256, 0, stream>>>(offs_e, cols_e, vals_e, F4, efeat, F5, NE); // A2 = emat@A + efeat
    gather_src2<<<gNr, b256, 0, stream>>>(offs_src, dsts_s, F5, efeat, F1, F2, NN);   // vf1, vf2
    gemm128<<<gN, b256, 0, stream>>>(F1, Wv, D, nullptr, out_v, NN, 1);               // vfeat_out

    // ---- psi2 + vMat path ----
    gemm128<<<gN, b256, 0, stream>>>(out_v, psi2_W, 2 * D, nullptr, F0, NN, 0);       // Qv
    gemm128<<<gE, b256, 0, stream>>>(efeat, psi2_W + D, 2 * D, psi2_b, F3, NE, 0);    // QeP = Qe + b2
    gather_spmm<<<gNr, b256, 0, stream>>>(offs_v, cols_v, vals_v, F2, nullptr, F1, NN); // vf2b = vmat@vf2
    gather_final<<<gEr, b256, 0, stream>>>(offs_dst, srcs_s, F0, F3, invDE, F1, F4, NE); // ef2
    gemm128<<<gE, b256, 0, stream>>>(F4, We, D, nullptr, out_e, NE, 1);               // efeat_out
}

// Round 4
// 669.924 us; speedup vs baseline: 2.3353x; 1.0917x over previous
//
#include <hip/hip_runtime.h>

#define NN 50000
#define NE 10000
#define NNZ_INC 400000
#define NNZ_E 80000
#define NNZ_V 400000
#define D 128
#define KC 32

#define NB_NE 5              // ceil(10000/2048)
#define NB_NN 25             // ceil(50000/2048)
#define NB_TOT (2*NB_NE + 2*NB_NN)   // 60

// ---------------- dense GEMM: out[M,128] = act(X[M,128] @ W[:,0:128].T + b) ----------
__global__ __launch_bounds__(256) void gemm128(
    const float* __restrict__ X, const float* __restrict__ W, int ldw,
    const float* __restrict__ bias, float* __restrict__ out, int M, int doRelu)
{
    __shared__ float XsT[KC][68];
    __shared__ float Ws[KC][132];
    const int tid = threadIdx.x;
    const int tx = tid & 31, ty = tid >> 5;
    const int row0 = blockIdx.x * 64;
    const int c0 = tx * 4;
    const int r0 = ty * 8;

    float acc[8][4];
#pragma unroll
    for (int r = 0; r < 8; ++r)
#pragma unroll
        for (int c = 0; c < 4; ++c) acc[r][c] = 0.f;

    for (int kc = 0; kc < D; kc += KC) {
        __syncthreads();
#pragma unroll
        for (int it = 0; it < 2; ++it) {
            int l = tid + it * 256;
            int r = l >> 3, k4 = l & 7;
            float4 v = make_float4(0.f, 0.f, 0.f, 0.f);
            int row = row0 + r;
            if (row < M) v = ((const float4*)(X + (size_t)row * D + kc))[k4];
            int k = k4 * 4;
            XsT[k + 0][r] = v.x; XsT[k + 1][r] = v.y;
            XsT[k + 2][r] = v.z; XsT[k + 3][r] = v.w;
        }
#pragma unroll
        for (int it = 0; it < 4; ++it) {
            int l = tid + it * 256;
            int o = l >> 3, k4 = l & 7;
            float4 w = ((const float4*)(W + (size_t)o * ldw + kc))[k4];
            int k = k4 * 4;
            Ws[k + 0][o] = w.x; Ws[k + 1][o] = w.y;
            Ws[k + 2][o] = w.z; Ws[k + 3][o] = w.w;
        }
        __syncthreads();
#pragma unroll
        for (int k = 0; k < KC; ++k) {
            const float4 a0 = *(const float4*)&XsT[k][r0];
            const float4 a1 = *(const float4*)&XsT[k][r0 + 4];
            const float4 b  = *(const float4*)&Ws[k][c0];
            float av[8] = {a0.x, a0.y, a0.z, a0.w, a1.x, a1.y, a1.z, a1.w};
            float bv[4] = {b.x, b.y, b.z, b.w};
#pragma unroll
            for (int r = 0; r < 8; ++r)
#pragma unroll
                for (int c = 0; c < 4; ++c)
                    acc[r][c] = fmaf(av[r], bv[c], acc[r][c]);
        }
    }

    float4 b4 = bias ? ((const float4*)bias)[tx] : make_float4(0.f, 0.f, 0.f, 0.f);
#pragma unroll
    for (int r = 0; r < 8; ++r) {
        int row = row0 + r0 + r;
        if (row < M) {
            float4 v;
            v.x = acc[r][0] + b4.x; v.y = acc[r][1] + b4.y;
            v.z = acc[r][2] + b4.z; v.w = acc[r][3] + b4.w;
            if (doRelu) {
                v.x = fmaxf(v.x, 0.f); v.y = fmaxf(v.y, 0.f);
                v.z = fmaxf(v.z, 0.f); v.w = fmaxf(v.w, 0.f);
            }
            ((float4*)(out + (size_t)row * D))[tx] = v;
        }
    }
}

// ---------------- fused histograms (range-partitioned grid) ---------------------------
__global__ void hist_all(const int* __restrict__ src, const int* __restrict__ dst,
                         int* __restrict__ cnt_src, int* __restrict__ cnt_dst,
                         const int* __restrict__ erows, int* __restrict__ cnt_e,
                         const int* __restrict__ vrows, int* __restrict__ cnt_v)
{
    int i = blockIdx.x * 256 + threadIdx.x;
    if (i < NNZ_INC) {
        atomicAdd(cnt_dst + dst[i], 1);
        atomicAdd(cnt_src + src[i], 1);
    } else if (i < NNZ_INC + NNZ_E) {
        atomicAdd(cnt_e + erows[i - NNZ_INC], 1);
    } else if (i < NNZ_INC + NNZ_E + NNZ_V) {
        atomicAdd(cnt_v + vrows[i - NNZ_INC - NNZ_E], 1);
    }
}

// ---------------- 3-phase batched scan over the 4 count arrays ------------------------
__device__ inline void scan_map(int b, const int* c0, const int* c1, const int* c2,
                                const int* c3, const int*& cnt, int& n, int& lb, int& off)
{
    if (b < NB_NE)                { cnt = c0; n = NE; lb = b;                     off = 0; }
    else if (b < NB_NE + NB_NN)   { cnt = c1; n = NN; lb = b - NB_NE;             off = NB_NE; }
    else if (b < 2*NB_NE + NB_NN) { cnt = c2; n = NE; lb = b - NB_NE - NB_NN;     off = NB_NE + NB_NN; }
    else                          { cnt = c3; n = NN; lb = b - 2*NB_NE - NB_NN;   off = 2*NB_NE + NB_NN; }
}

__global__ __launch_bounds__(256) void scan_partial(
    const int* __restrict__ c0, const int* __restrict__ c1,
    const int* __restrict__ c2, const int* __restrict__ c3, int* __restrict__ bsums)
{
    __shared__ int wsum[4];
    const int* cnt; int n, lb, off;
    scan_map(blockIdx.x, c0, c1, c2, c3, cnt, n, lb, off);
    int lane = threadIdx.x & 63, wid = threadIdx.x >> 6;
    int i0 = lb * 2048 + threadIdx.x * 8;
    int s = 0;
#pragma unroll
    for (int k = 0; k < 8; ++k) {
        int i = i0 + k;
        if (i < n) s += cnt[i];
    }
#pragma unroll
    for (int d = 1; d < 64; d <<= 1) s += __shfl_xor(s, d, 64);
    if (lane == 0) wsum[wid] = s;
    __syncthreads();
    if (threadIdx.x == 0) bsums[off + lb] = wsum[0] + wsum[1] + wsum[2] + wsum[3];
}

__global__ __launch_bounds__(256) void scan_bsums(
    int* __restrict__ bsums, int* o0, int* o1, int* o2, int* o3)
{
    int wid = threadIdx.x >> 6, lane = threadIdx.x & 63;
    int st, nb, n; int* offs;
    switch (wid) {
        case 0:  st = 0;               nb = NB_NE; n = NE; offs = o0; break;
        case 1:  st = NB_NE;           nb = NB_NN; n = NN; offs = o1; break;
        case 2:  st = NB_NE + NB_NN;   nb = NB_NE; n = NE; offs = o2; break;
        default: st = 2*NB_NE + NB_NN; nb = NB_NN; n = NN; offs = o3; break;
    }
    int v = (lane < nb) ? bsums[st + lane] : 0;
    int incl = v;
#pragma unroll
    for (int s = 1; s < 64; s <<= 1) {
        int t = __shfl_up(incl, s, 64);
        if (lane >= s) incl += t;
    }
    if (lane < nb) bsums[st + lane] = incl - v;
    if (lane == 63) offs[n] = incl;
}

__global__ __launch_bounds__(256) void scan_final(
    const int* __restrict__ c0, int* __restrict__ o0, int* __restrict__ u0,
    const int* __restrict__ c1, int* __restrict__ o1, int* __restrict__ u1,
    const int* __restrict__ c2, int* __restrict__ o2, int* __restrict__ u2,
    const int* __restrict__ c3, int* __restrict__ o3, int* __restrict__ u3,
    const int* __restrict__ bsums)
{
    __shared__ int wsum[4];
    const int* cnt; int n, lb, off;
    scan_map(blockIdx.x, c0, c1, c2, c3, cnt, n, lb, off);
    int* offs; int* cur;
    int b = blockIdx.x;
    if (b < NB_NE)                { offs = o0; cur = u0; }
    else if (b < NB_NE + NB_NN)   { offs = o1; cur = u1; }
    else if (b < 2*NB_NE + NB_NN) { offs = o2; cur = u2; }
    else                          { offs = o3; cur = u3; }
    int base = bsums[off + lb];
    int lane = threadIdx.x & 63, wid = threadIdx.x >> 6;
    int i0 = lb * 2048 + threadIdx.x * 8;
    int v[8]; int tsum = 0;
#pragma unroll
    for (int k = 0; k < 8; ++k) {
        int i = i0 + k;
        v[k] = (i < n) ? cnt[i] : 0;
        tsum += v[k];
    }
    int incl = tsum;
#pragma unroll
    for (int s = 1; s < 64; s <<= 1) {
        int t = __shfl_up(incl, s, 64);
        if (lane >= s) incl += t;
    }
    if (lane == 63) wsum[wid] = incl;
    __syncthreads();
    int woff = 0;
    for (int w = 0; w < wid; ++w) woff += wsum[w];
    int run = base + woff + incl - tsum;
#pragma unroll
    for (int k = 0; k < 8; ++k) {
        int i = i0 + k;
        if (i < n) { offs[i] = run; cur[i] = run; }
        run += v[k];
    }
}

// ---------------- fused fills (range-partitioned grid) --------------------------------
__global__ void fill_all(
    const int* __restrict__ src, const int* __restrict__ dst,
    int* __restrict__ cur_dst, int* __restrict__ srcs_s,
    int* __restrict__ cur_src, int* __restrict__ dsts_s,
    const int* __restrict__ erows, const int* __restrict__ ecols, const float* __restrict__ evals,
    int* __restrict__ cur_e, int* __restrict__ cols_e, float* __restrict__ vals_e,
    const int* __restrict__ vrows, const int* __restrict__ vcols, const float* __restrict__ vvals,
    int* __restrict__ cur_v, int* __restrict__ cols_v, float* __restrict__ vals_v)
{
    int i = blockIdx.x * 256 + threadIdx.x;
    if (i < NNZ_INC) {
        int s = src[i], d = dst[i];
        srcs_s[atomicAdd(cur_dst + d, 1)] = s;
        dsts_s[atomicAdd(cur_src + s, 1)] = d;
    } else if (i < NNZ_INC + NNZ_E) {
        int j = i - NNZ_INC;
        int p = atomicAdd(cur_e + erows[j], 1);
        cols_e[p] = ecols[j];
        vals_e[p] = evals[j];
    } else if (i < NNZ_INC + NNZ_E + NNZ_V) {
        int j = i - NNZ_INC - NNZ_E;
        int p = atomicAdd(cur_v + vrows[j], 1);
        cols_v[p] = vcols[j];
        vals_v[p] = vvals[j];
    }
}

// ---------------- A[e,:] = sum_s invDV[s]*Pv[s,:] + (sum_s invDV[s])*PeP[e,:] --------
__global__ __launch_bounds__(256) void gather_A(
    const int* __restrict__ offs, const int* __restrict__ srcs,
    const float* __restrict__ invDV, const float* __restrict__ Pv,
    const float* __restrict__ PeP, float* __restrict__ A, int E)
{
    int e = blockIdx.x * 4 + (threadIdx.x >> 6);
    int l = threadIdx.x & 63;
    if (e >= E) return;
    int j0 = offs[e], j1 = offs[e + 1];
    float2 acc = make_float2(0.f, 0.f);
    float wsum = 0.f;
    for (int j = j0; j < j1; ++j) {
        int s = srcs[j];
        float w = invDV[s];
        float2 p = ((const float2*)(Pv + (size_t)s * D))[l];
        wsum += w;
        acc.x = fmaf(w, p.x, acc.x);
        acc.y = fmaf(w, p.y, acc.y);
    }
    float2 pe = ((const float2*)(PeP + (size_t)e * D))[l];
    acc.x = fmaf(wsum, pe.x, acc.x);
    acc.y = fmaf(wsum, pe.y, acc.y);
    ((float2*)(A + (size_t)e * D))[l] = acc;
}

// ---------------- Y[r,:] = (addend?addend[r,:]:0) + sum_j vals_j * X[cols_j,:] -------
__global__ __launch_bounds__(256) void gather_spmm(
    const int* __restrict__ offs, const int* __restrict__ cols,
    const float* __restrict__ vals, const float* __restrict__ X,
    const float* __restrict__ addend, float* __restrict__ Y, int R)
{
    int r = blockIdx.x * 4 + (threadIdx.x >> 6);
    int l = threadIdx.x & 63;
    if (r >= R) return;
    int j0 = offs[r], j1 = offs[r + 1];
    float2 acc = addend ? ((const float2*)(addend + (size_t)r * D))[l]
                        : make_float2(0.f, 0.f);
    for (int j = j0; j < j1; ++j) {
        int c = cols[j];
        float v = vals[j];
        float2 x = ((const float2*)(X + (size_t)c * D))[l];
        acc.x = fmaf(v, x.x, acc.x);
        acc.y = fmaf(v, x.y, acc.y);
    }
    ((float2*)(Y + (size_t)r * D))[l] = acc;
}

// ---------------- vf1[n,:] = sum_d ef1[d,:]; vf2[n,:] = sum_d ef0[d,:] ---------------
__global__ __launch_bounds__(256) void gather_src2(
    const int* __restrict__ offs, const int* __restrict__ dsts,
    const float* __restrict__ ef1, const float* __restrict__ ef0,
    float* __restrict__ vf1, float* __restrict__ vf2, int N)
{
    int n = blockIdx.x * 4 + (threadIdx.x >> 6);
    int l = threadIdx.x & 63;
    if (n >= N) return;
    int j0 = offs[n], j1 = offs[n + 1];
    float2 a1 = make_float2(0.f, 0.f), a2 = make_float2(0.f, 0.f);
    for (int j = j0; j < j1; ++j) {
        int d = dsts[j];
        float2 x1 = ((const float2*)(ef1 + (size_t)d * D))[l];
        float2 x0 = ((const float2*)(ef0 + (size_t)d * D))[l];
        a1.x += x1.x; a1.y += x1.y;
        a2.x += x0.x; a2.y += x0.y;
    }
    ((float2*)(vf1 + (size_t)n * D))[l] = a1;
    ((float2*)(vf2 + (size_t)n * D))[l] = a2;
}

// ------- ef2[e,:] = (sum_s Qv[s,:] + deg[e]*QeP[e,:]) * invDE[e] + sum_s vf2b[s,:] ---
__global__ __launch_bounds__(256) void gather_final(
    const int* __restrict__ offs, const int* __restrict__ srcs,
    const float* __restrict__ Qv, const float* __restrict__ QeP,
    const float* __restrict__ invDE, const float* __restrict__ vf2b,
    float* __restrict__ ef2, int E)
{
    int e = blockIdx.x * 4 + (threadIdx.x >> 6);
    int l = threadIdx.x & 63;
    if (e >= E) return;
    int j0 = offs[e], j1 = offs[e + 1];
    float deg = (float)(j1 - j0);
    float2 aq = make_float2(0.f, 0.f), av = make_float2(0.f, 0.f);
    for (int j = j0; j < j1; ++j) {
        int s = srcs[j];
        float2 q = ((const float2*)(Qv + (size_t)s * D))[l];
        float2 v = ((const float2*)(vf2b + (size_t)s * D))[l];
        aq.x += q.x; aq.y += q.y;
        av.x += v.x; av.y += v.y;
    }
    float2 qe = ((const float2*)(QeP + (size_t)e * D))[l];
    float ide = invDE[e];
    float2 out;
    out.x = fmaf(deg, qe.x, aq.x) * ide + av.x;
    out.y = fmaf(deg, qe.y, aq.y) * ide + av.y;
    ((float2*)(ef2 + (size_t)e * D))[l] = out;
}

extern "C" void kernel_launch(void* const* d_in, const int* in_sizes, int n_in,
                              void* d_out, int out_size, void* d_ws, size_t ws_size,
                              hipStream_t stream)
{
    (void)in_sizes; (void)n_in; (void)out_size; (void)ws_size;
    const float* vfeat     = (const float*)d_in[0];
    const float* efeat     = (const float*)d_in[1];
    const float* invDV     = (const float*)d_in[2];
    const float* invDE     = (const float*)d_in[3];
    const int*   inc_src   = (const int*)d_in[4];
    const int*   inc_dst   = (const int*)d_in[5];
    const int*   emat_rows = (const int*)d_in[6];
    const int*   emat_cols = (const int*)d_in[7];
    const float* emat_vals = (const float*)d_in[8];
    const int*   vmat_rows = (const int*)d_in[9];
    const int*   vmat_cols = (const int*)d_in[10];
    const float* vmat_vals = (const float*)d_in[11];
    const float* Wv        = (const float*)d_in[12];
    const float* We        = (const float*)d_in[13];
    const float* psi1_W    = (const float*)d_in[14];
    const float* psi1_b    = (const float*)d_in[15];
    const float* psi2_W    = (const float*)d_in[16];
    const float* psi2_b    = (const float*)d_in[17];

    const size_t ND = (size_t)NN * D;
    const size_t ED = (size_t)NE * D;

    float* F0 = (float*)d_ws;    // Pv -> Qv           [NN,D]
    float* F1 = F0 + ND;         // vf1 -> vf2b        [NN,D]
    float* F2 = F1 + ND;         // vf2                [NN,D]
    float* F3 = F2 + ND;         // PeP -> QeP         [NE,D]
    float* F4 = F3 + ED;         // A  -> ef2          [NE,D]
    float* F5 = F4 + ED;         // A2 (_efeat)        [NE,D]

    int* ip       = (int*)(F5 + ED);
    int* cnt_dst  = ip;  ip += NE;
    int* cnt_src  = ip;  ip += NN;
    int* cnt_e    = ip;  ip += NE;
    int* cnt_v    = ip;  ip += NN;
    int* offs_dst = ip;  ip += NE + 1;
    int* cur_dst  = ip;  ip += NE;
    int* srcs_s   = ip;  ip += NNZ_INC;
    int* offs_src = ip;  ip += NN + 1;
    int* cur_src  = ip;  ip += NN;
    int* dsts_s   = ip;  ip += NNZ_INC;
    int* offs_e   = ip;  ip += NE + 1;
    int* cur_e    = ip;  ip += NE;
    int* cols_e   = ip;  ip += NNZ_E;
    float* vals_e = (float*)ip; ip += NNZ_E;
    int* offs_v   = ip;  ip += NN + 1;
    int* cur_v    = ip;  ip += NN;
    int* cols_v   = ip;  ip += NNZ_V;
    float* vals_v = (float*)ip; ip += NNZ_V;
    int* bsums    = ip;  ip += NB_TOT;

    float* out_v = (float*)d_out;     // [NN,D]
    float* out_e = out_v + ND;        // [NE,D]

    dim3 b256(256);
    int gN  = (NN + 63) / 64, gE = (NE + 63) / 64;
    int gNr = (NN + 3) / 4,  gEr = (NE + 3) / 4;
    int gNNZ = (NNZ_INC + NNZ_E + NNZ_V + 255) / 256;

    // ---- CSR build ----
    hipMemsetAsync(cnt_dst, 0, (size_t)(2 * NE + 2 * NN) * sizeof(int), stream);
    hist_all<<<gNNZ, b256, 0, stream>>>(inc_src, inc_dst, cnt_src, cnt_dst,
                                        emat_rows, cnt_e, vmat_rows, cnt_v);
    scan_partial<<<NB_TOT, b256, 0, stream>>>(cnt_dst, cnt_src, cnt_e, cnt_v, bsums);
    scan_bsums<<<1, b256, 0, stream>>>(bsums, offs_dst, offs_src, offs_e, offs_v);
    scan_final<<<NB_TOT, b256, 0, stream>>>(cnt_dst, offs_dst, cur_dst,
                                            cnt_src, offs_src, cur_src,
                                            cnt_e,   offs_e,   cur_e,
                                            cnt_v,   offs_v,   cur_v, bsums);
    fill_all<<<gNNZ, b256, 0, stream>>>(inc_src, inc_dst, cur_dst, srcs_s, cur_src, dsts_s,
                                        emat_rows, emat_cols, emat_vals, cur_e, cols_e, vals_e,
                                        vmat_rows, vmat_cols, vmat_vals, cur_v, cols_v, vals_v);

    // ---- psi1 path ----
    gemm128<<<gN, b256, 0, stream>>>(vfeat, psi1_W, 2 * D, nullptr, F0, NN, 0);       // Pv
    gemm128<<<gE, b256, 0, stream>>>(efeat, psi1_W + D, 2 * D, psi1_b, F3, NE, 0);    // PeP = Pe + b1
    gather_A<<<gEr, b256, 0, stream>>>(offs_dst, srcs_s, invDV, F0, F3, F4, NE);      // A
    gather_spmm<<<gEr, b256, 0, stream>>>(offs_e, cols_e, vals_e, F4, efeat, F5, NE); // A2 = emat@A + efeat
    gather_src2<<<gNr, b256, 0, stream>>>(offs_src, dsts_s, F5, efeat, F1, F2, NN);   // vf1, vf2
    gemm128<<<gN, b256, 0, stream>>>(F1, Wv, D, nullptr, out_v, NN, 1);               // vfeat_out

    // ---- psi2 + vMat path ----
    gemm128<<<gN, b256, 0, stream>>>(out_v, psi2_W, 2 * D, nullptr, F0, NN, 0);       // Qv
    gemm128<<<gE, b256, 0, stream>>>(efeat, psi2_W + D, 2 * D, psi2_b, F3, NE, 0);    // QeP = Qe + b2
    gather_spmm<<<gNr, b256, 0, stream>>>(offs_v, cols_v, vals_v, F2, nullptr, F1, NN); // vf2b = vmat@vf2
    gather_final<<<gEr, b256, 0, stream>>>(offs_dst, srcs_s, F0, F3, invDE, F1, F4, NE); // ef2
    gemm128<<<gE, b256, 0, stream>>>(F4, We, D, nullptr, out_e, NE, 1);               // efeat_out
}

// Round 5
// 590.138 us; speedup vs baseline: 2.6510x; 1.1352x over previous
//
#include <hip/hip_runtime.h>

#define NN 50000
#define NE 10000
#define NNZ_INC 400000
#define NNZ_E 80000
#define NNZ_V 400000
#define D 128
#define KC 32

#define NB_NE 5              // ceil(10000/2048)
#define NB_NN 25             // ceil(50000/2048)
#define NB_TOT (2*NB_NE + 2*NB_NN)   // 60

// ---------------- dense GEMM: out[M,128] = act(X[M,128] @ W[:,0:128].T + b) ----------
__global__ __launch_bounds__(256) void gemm128(
    const float* __restrict__ X, const float* __restrict__ W, int ldw,
    const float* __restrict__ bias, float* __restrict__ out, int M, int doRelu)
{
    __shared__ float XsT[KC][68];
    __shared__ float Ws[KC][132];
    const int tid = threadIdx.x;
    const int tx = tid & 31, ty = tid >> 5;
    const int row0 = blockIdx.x * 64;
    const int c0 = tx * 4;
    const int r0 = ty * 8;

    float acc[8][4];
#pragma unroll
    for (int r = 0; r < 8; ++r)
#pragma unroll
        for (int c = 0; c < 4; ++c) acc[r][c] = 0.f;

    for (int kc = 0; kc < D; kc += KC) {
        __syncthreads();
#pragma unroll
        for (int it = 0; it < 2; ++it) {
            int l = tid + it * 256;
            int r = l >> 3, k4 = l & 7;
            float4 v = make_float4(0.f, 0.f, 0.f, 0.f);
            int row = row0 + r;
            if (row < M) v = ((const float4*)(X + (size_t)row * D + kc))[k4];
            int k = k4 * 4;
            XsT[k + 0][r] = v.x; XsT[k + 1][r] = v.y;
            XsT[k + 2][r] = v.z; XsT[k + 3][r] = v.w;
        }
#pragma unroll
        for (int it = 0; it < 4; ++it) {
            int l = tid + it * 256;
            int o = l >> 3, k4 = l & 7;
            float4 w = ((const float4*)(W + (size_t)o * ldw + kc))[k4];
            int k = k4 * 4;
            Ws[k + 0][o] = w.x; Ws[k + 1][o] = w.y;
            Ws[k + 2][o] = w.z; Ws[k + 3][o] = w.w;
        }
        __syncthreads();
#pragma unroll
        for (int k = 0; k < KC; ++k) {
            const float4 a0 = *(const float4*)&XsT[k][r0];
            const float4 a1 = *(const float4*)&XsT[k][r0 + 4];
            const float4 b  = *(const float4*)&Ws[k][c0];
            float av[8] = {a0.x, a0.y, a0.z, a0.w, a1.x, a1.y, a1.z, a1.w};
            float bv[4] = {b.x, b.y, b.z, b.w};
#pragma unroll
            for (int r = 0; r < 8; ++r)
#pragma unroll
                for (int c = 0; c < 4; ++c)
                    acc[r][c] = fmaf(av[r], bv[c], acc[r][c]);
        }
    }

    float4 b4 = bias ? ((const float4*)bias)[tx] : make_float4(0.f, 0.f, 0.f, 0.f);
#pragma unroll
    for (int r = 0; r < 8; ++r) {
        int row = row0 + r0 + r;
        if (row < M) {
            float4 v;
            v.x = acc[r][0] + b4.x; v.y = acc[r][1] + b4.y;
            v.z = acc[r][2] + b4.z; v.w = acc[r][3] + b4.w;
            if (doRelu) {
                v.x = fmaxf(v.x, 0.f); v.y = fmaxf(v.y, 0.f);
                v.z = fmaxf(v.z, 0.f); v.w = fmaxf(v.w, 0.f);
            }
            ((float4*)(out + (size_t)row * D))[tx] = v;
        }
    }
}

// ---------------- fused histograms (range-partitioned grid) ---------------------------
__global__ void hist_all(const int* __restrict__ src, const int* __restrict__ dst,
                         int* __restrict__ cnt_src, int* __restrict__ cnt_dst,
                         const int* __restrict__ erows, int* __restrict__ cnt_e,
                         const int* __restrict__ vrows, int* __restrict__ cnt_v)
{
    int i = blockIdx.x * 256 + threadIdx.x;
    if (i < NNZ_INC) {
        atomicAdd(cnt_dst + dst[i], 1);
        atomicAdd(cnt_src + src[i], 1);
    } else if (i < NNZ_INC + NNZ_E) {
        atomicAdd(cnt_e + erows[i - NNZ_INC], 1);
    } else if (i < NNZ_INC + NNZ_E + NNZ_V) {
        atomicAdd(cnt_v + vrows[i - NNZ_INC - NNZ_E], 1);
    }
}

// ---------------- 3-phase batched scan over the 4 count arrays ------------------------
__device__ inline void scan_map(int b, const int* c0, const int* c1, const int* c2,
                                const int* c3, const int*& cnt, int& n, int& lb, int& off)
{
    if (b < NB_NE)                { cnt = c0; n = NE; lb = b;                     off = 0; }
    else if (b < NB_NE + NB_NN)   { cnt = c1; n = NN; lb = b - NB_NE;             off = NB_NE; }
    else if (b < 2*NB_NE + NB_NN) { cnt = c2; n = NE; lb = b - NB_NE - NB_NN;     off = NB_NE + NB_NN; }
    else                          { cnt = c3; n = NN; lb = b - 2*NB_NE - NB_NN;   off = 2*NB_NE + NB_NN; }
}

__global__ __launch_bounds__(256) void scan_partial(
    const int* __restrict__ c0, const int* __restrict__ c1,
    const int* __restrict__ c2, const int* __restrict__ c3, int* __restrict__ bsums)
{
    __shared__ int wsum[4];
    const int* cnt; int n, lb, off;
    scan_map(blockIdx.x, c0, c1, c2, c3, cnt, n, lb, off);
    int lane = threadIdx.x & 63, wid = threadIdx.x >> 6;
    int i0 = lb * 2048 + threadIdx.x * 8;
    int s = 0;
#pragma unroll
    for (int k = 0; k < 8; ++k) {
        int i = i0 + k;
        if (i < n) s += cnt[i];
    }
#pragma unroll
    for (int d = 1; d < 64; d <<= 1) s += __shfl_xor(s, d, 64);
    if (lane == 0) wsum[wid] = s;
    __syncthreads();
    if (threadIdx.x == 0) bsums[off + lb] = wsum[0] + wsum[1] + wsum[2] + wsum[3];
}

__global__ __launch_bounds__(256) void scan_bsums(
    int* __restrict__ bsums, int* o0, int* o1, int* o2, int* o3)
{
    int wid = threadIdx.x >> 6, lane = threadIdx.x & 63;
    int st, nb, n; int* offs;
    switch (wid) {
        case 0:  st = 0;               nb = NB_NE; n = NE; offs = o0; break;
        case 1:  st = NB_NE;           nb = NB_NN; n = NN; offs = o1; break;
        case 2:  st = NB_NE + NB_NN;   nb = NB_NE; n = NE; offs = o2; break;
        default: st = 2*NB_NE + NB_NN; nb = NB_NN; n = NN; offs = o3; break;
    }
    int v = (lane < nb) ? bsums[st + lane] : 0;
    int incl = v;
#pragma unroll
    for (int s = 1; s < 64; s <<= 1) {
        int t = __shfl_up(incl, s, 64);
        if (lane >= s) incl += t;
    }
    if (lane < nb) bsums[st + lane] = incl - v;
    if (lane == 63) offs[n] = incl;
}

__global__ __launch_bounds__(256) void scan_final(
    const int* __restrict__ c0, int* __restrict__ o0, int* __restrict__ u0,
    const int* __restrict__ c1, int* __restrict__ o1, int* __restrict__ u1,
    const int* __restrict__ c2, int* __restrict__ o2, int* __restrict__ u2,
    const int* __restrict__ c3, int* __restrict__ o3, int* __restrict__ u3,
    const int* __restrict__ bsums)
{
    __shared__ int wsum[4];
    const int* cnt; int n, lb, off;
    scan_map(blockIdx.x, c0, c1, c2, c3, cnt, n, lb, off);
    int* offs; int* cur;
    int b = blockIdx.x;
    if (b < NB_NE)                { offs = o0; cur = u0; }
    else if (b < NB_NE + NB_NN)   { offs = o1; cur = u1; }
    else if (b < 2*NB_NE + NB_NN) { offs = o2; cur = u2; }
    else                          { offs = o3; cur = u3; }
    int base = bsums[off + lb];
    int lane = threadIdx.x & 63, wid = threadIdx.x >> 6;
    int i0 = lb * 2048 + threadIdx.x * 8;
    int v[8]; int tsum = 0;
#pragma unroll
    for (int k = 0; k < 8; ++k) {
        int i = i0 + k;
        v[k] = (i < n) ? cnt[i] : 0;
        tsum += v[k];
    }
    int incl = tsum;
#pragma unroll
    for (int s = 1; s < 64; s <<= 1) {
        int t = __shfl_up(incl, s, 64);
        if (lane >= s) incl += t;
    }
    if (lane == 63) wsum[wid] = incl;
    __syncthreads();
    int woff = 0;
    for (int w = 0; w < wid; ++w) woff += wsum[w];
    int run = base + woff + incl - tsum;
#pragma unroll
    for (int k = 0; k < 8; ++k) {
        int i = i0 + k;
        if (i < n) { offs[i] = run; cur[i] = run; }
        run += v[k];
    }
}

// ---------------- fused fills; emat/vmat entries packed as int2 (col, val) ------------
__global__ void fill_all(
    const int* __restrict__ src, const int* __restrict__ dst,
    int* __restrict__ cur_dst, int* __restrict__ srcs_s,
    int* __restrict__ cur_src, int* __restrict__ dsts_s,
    const int* __restrict__ erows, const int* __restrict__ ecols, const float* __restrict__ evals,
    int* __restrict__ cur_e, int2* __restrict__ ev_e,
    const int* __restrict__ vrows, const int* __restrict__ vcols, const float* __restrict__ vvals,
    int* __restrict__ cur_v, int2* __restrict__ ev_v)
{
    int i = blockIdx.x * 256 + threadIdx.x;
    if (i < NNZ_INC) {
        int s = src[i], d = dst[i];
        srcs_s[atomicAdd(cur_dst + d, 1)] = s;
        dsts_s[atomicAdd(cur_src + s, 1)] = d;
    } else if (i < NNZ_INC + NNZ_E) {
        int j = i - NNZ_INC;
        int p = atomicAdd(cur_e + erows[j], 1);
        ev_e[p] = make_int2(ecols[j], __float_as_int(evals[j]));
    } else if (i < NNZ_INC + NNZ_E + NNZ_V) {
        int j = i - NNZ_INC - NNZ_E;
        int p = atomicAdd(cur_v + vrows[j], 1);
        ev_v[p] = make_int2(vcols[j], __float_as_int(vvals[j]));
    }
}

// ---------------- A[e,:] = sum_s invDV[s]*Pv[s,:] + (sum_s invDV[s])*PeP[e,:] --------
__global__ __launch_bounds__(256) void gather_A(
    const int* __restrict__ offs, const int* __restrict__ srcs,
    const float* __restrict__ invDV, const float* __restrict__ Pv,
    const float* __restrict__ PeP, float* __restrict__ A, int E)
{
    int e = blockIdx.x * 4 + (threadIdx.x >> 6);
    int l = threadIdx.x & 63;
    if (e >= E) return;
    int j0 = offs[e], j1 = offs[e + 1];
    float2 acc = make_float2(0.f, 0.f);
    float wsum = 0.f;
    int j = j0;
    for (; j + 3 < j1; j += 4) {
        int s0 = srcs[j], s1 = srcs[j + 1], s2 = srcs[j + 2], s3 = srcs[j + 3];
        float w0 = invDV[s0], w1 = invDV[s1], w2 = invDV[s2], w3 = invDV[s3];
        float2 p0 = ((const float2*)(Pv + (size_t)s0 * D))[l];
        float2 p1 = ((const float2*)(Pv + (size_t)s1 * D))[l];
        float2 p2 = ((const float2*)(Pv + (size_t)s2 * D))[l];
        float2 p3 = ((const float2*)(Pv + (size_t)s3 * D))[l];
        wsum += w0 + w1 + w2 + w3;
        acc.x = fmaf(w0, p0.x, fmaf(w1, p1.x, fmaf(w2, p2.x, fmaf(w3, p3.x, acc.x))));
        acc.y = fmaf(w0, p0.y, fmaf(w1, p1.y, fmaf(w2, p2.y, fmaf(w3, p3.y, acc.y))));
    }
    for (; j < j1; ++j) {
        int s = srcs[j];
        float w = invDV[s];
        float2 p = ((const float2*)(Pv + (size_t)s * D))[l];
        wsum += w;
        acc.x = fmaf(w, p.x, acc.x);
        acc.y = fmaf(w, p.y, acc.y);
    }
    float2 pe = ((const float2*)(PeP + (size_t)e * D))[l];
    acc.x = fmaf(wsum, pe.x, acc.x);
    acc.y = fmaf(wsum, pe.y, acc.y);
    ((float2*)(A + (size_t)e * D))[l] = acc;
}

// -------- Y[r,:] = (addend?addend[r,:]:0) + sum_j val_j * X[col_j,:]  (packed int2) ---
__global__ __launch_bounds__(256) void gather_spmm(
    const int* __restrict__ offs, const int2* __restrict__ ev,
    const float* __restrict__ X, const float* __restrict__ addend,
    float* __restrict__ Y, int R)
{
    int r = blockIdx.x * 4 + (threadIdx.x >> 6);
    int l = threadIdx.x & 63;
    if (r >= R) return;
    int j0 = offs[r], j1 = offs[r + 1];
    float2 acc = addend ? ((const float2*)(addend + (size_t)r * D))[l]
                        : make_float2(0.f, 0.f);
    int j = j0;
    for (; j + 3 < j1; j += 4) {
        int2 e0 = ev[j], e1 = ev[j + 1], e2 = ev[j + 2], e3 = ev[j + 3];
        float2 x0 = ((const float2*)(X + (size_t)e0.x * D))[l];
        float2 x1 = ((const float2*)(X + (size_t)e1.x * D))[l];
        float2 x2 = ((const float2*)(X + (size_t)e2.x * D))[l];
        float2 x3 = ((const float2*)(X + (size_t)e3.x * D))[l];
        float v0 = __int_as_float(e0.y), v1 = __int_as_float(e1.y);
        float v2 = __int_as_float(e2.y), v3 = __int_as_float(e3.y);
        acc.x = fmaf(v0, x0.x, fmaf(v1, x1.x, fmaf(v2, x2.x, fmaf(v3, x3.x, acc.x))));
        acc.y = fmaf(v0, x0.y, fmaf(v1, x1.y, fmaf(v2, x2.y, fmaf(v3, x3.y, acc.y))));
    }
    for (; j < j1; ++j) {
        int2 e = ev[j];
        float2 x = ((const float2*)(X + (size_t)e.x * D))[l];
        float v = __int_as_float(e.y);
        acc.x = fmaf(v, x.x, acc.x);
        acc.y = fmaf(v, x.y, acc.y);
    }
    ((float2*)(Y + (size_t)r * D))[l] = acc;
}

// ---------------- vf1[n,:] = sum_d ef1[d,:]; vf2[n,:] = sum_d ef0[d,:] ---------------
__global__ __launch_bounds__(256) void gather_src2(
    const int* __restrict__ offs, const int* __restrict__ dsts,
    const float* __restrict__ ef1, const float* __restrict__ ef0,
    float* __restrict__ vf1, float* __restrict__ vf2, int N)
{
    int n = blockIdx.x * 4 + (threadIdx.x >> 6);
    int l = threadIdx.x & 63;
    if (n >= N) return;
    int j0 = offs[n], j1 = offs[n + 1];
    float2 a1 = make_float2(0.f, 0.f), a2 = make_float2(0.f, 0.f);
    int j = j0;
    for (; j + 1 < j1; j += 2) {
        int d0 = dsts[j], d1 = dsts[j + 1];
        float2 p0 = ((const float2*)(ef1 + (size_t)d0 * D))[l];
        float2 q0 = ((const float2*)(ef0 + (size_t)d0 * D))[l];
        float2 p1 = ((const float2*)(ef1 + (size_t)d1 * D))[l];
        float2 q1 = ((const float2*)(ef0 + (size_t)d1 * D))[l];
        a1.x += p0.x + p1.x; a1.y += p0.y + p1.y;
        a2.x += q0.x + q1.x; a2.y += q0.y + q1.y;
    }
    for (; j < j1; ++j) {
        int d = dsts[j];
        float2 x1 = ((const float2*)(ef1 + (size_t)d * D))[l];
        float2 x0 = ((const float2*)(ef0 + (size_t)d * D))[l];
        a1.x += x1.x; a1.y += x1.y;
        a2.x += x0.x; a2.y += x0.y;
    }
    ((float2*)(vf1 + (size_t)n * D))[l] = a1;
    ((float2*)(vf2 + (size_t)n * D))[l] = a2;
}

// ------- ef2[e,:] = (sum_s Qv[s,:] + deg[e]*QeP[e,:]) * invDE[e] + sum_s vf2b[s,:] ---
__global__ __launch_bounds__(256) void gather_final(
    const int* __restrict__ offs, const int* __restrict__ srcs,
    const float* __restrict__ Qv, const float* __restrict__ QeP,
    const float* __restrict__ invDE, const float* __restrict__ vf2b,
    float* __restrict__ ef2, int E)
{
    int e = blockIdx.x * 4 + (threadIdx.x >> 6);
    int l = threadIdx.x & 63;
    if (e >= E) return;
    int j0 = offs[e], j1 = offs[e + 1];
    float deg = (float)(j1 - j0);
    float2 aq = make_float2(0.f, 0.f), av = make_float2(0.f, 0.f);
    int j = j0;
    for (; j + 1 < j1; j += 2) {
        int s0 = srcs[j], s1 = srcs[j + 1];
        float2 q0 = ((const float2*)(Qv + (size_t)s0 * D))[l];
        float2 v0 = ((const float2*)(vf2b + (size_t)s0 * D))[l];
        float2 q1 = ((const float2*)(Qv + (size_t)s1 * D))[l];
        float2 v1 = ((const float2*)(vf2b + (size_t)s1 * D))[l];
        aq.x += q0.x + q1.x; aq.y += q0.y + q1.y;
        av.x += v0.x + v1.x; av.y += v0.y + v1.y;
    }
    for (; j < j1; ++j) {
        int s = srcs[j];
        float2 q = ((const float2*)(Qv + (size_t)s * D))[l];
        float2 v = ((const float2*)(vf2b + (size_t)s * D))[l];
        aq.x += q.x; aq.y += q.y;
        av.x += v.x; av.y += v.y;
    }
    float2 qe = ((const float2*)(QeP + (size_t)e * D))[l];
    float ide = invDE[e];
    float2 out;
    out.x = fmaf(deg, qe.x, aq.x) * ide + av.x;
    out.y = fmaf(deg, qe.y, aq.y) * ide + av.y;
    ((float2*)(ef2 + (size_t)e * D))[l] = out;
}

extern "C" void kernel_launch(void* const* d_in, const int* in_sizes, int n_in,
                              void* d_out, int out_size, void* d_ws, size_t ws_size,
                              hipStream_t stream)
{
    (void)in_sizes; (void)n_in; (void)out_size; (void)ws_size;
    const float* vfeat     = (const float*)d_in[0];
    const float* efeat     = (const float*)d_in[1];
    const float* invDV     = (const float*)d_in[2];
    const float* invDE     = (const float*)d_in[3];
    const int*   inc_src   = (const int*)d_in[4];
    const int*   inc_dst   = (const int*)d_in[5];
    const int*   emat_rows = (const int*)d_in[6];
    const int*   emat_cols = (const int*)d_in[7];
    const float* emat_vals = (const float*)d_in[8];
    const int*   vmat_rows = (const int*)d_in[9];
    const int*   vmat_cols = (const int*)d_in[10];
    const float* vmat_vals = (const float*)d_in[11];
    const float* Wv        = (const float*)d_in[12];
    const float* We        = (const float*)d_in[13];
    const float* psi1_W    = (const float*)d_in[14];
    const float* psi1_b    = (const float*)d_in[15];
    const float* psi2_W    = (const float*)d_in[16];
    const float* psi2_b    = (const float*)d_in[17];

    const size_t ND = (size_t)NN * D;
    const size_t ED = (size_t)NE * D;

    float* F0 = (float*)d_ws;    // Pv -> Qv           [NN,D]
    float* F1 = F0 + ND;         // vf1 -> vf2b        [NN,D]
    float* F2 = F1 + ND;         // vf2                [NN,D]
    float* F3 = F2 + ND;         // PeP -> QeP         [NE,D]
    float* F4 = F3 + ED;         // A  -> ef2          [NE,D]
    float* F5 = F4 + ED;         // A2 (_efeat)        [NE,D]

    int* ip       = (int*)(F5 + ED);
    int* cnt_dst  = ip;  ip += NE;
    int* cnt_src  = ip;  ip += NN;
    int* cnt_e    = ip;  ip += NE;
    int* cnt_v    = ip;  ip += NN;
    int* offs_dst = ip;  ip += NE + 1;
    int* cur_dst  = ip;  ip += NE;
    int* srcs_s   = ip;  ip += NNZ_INC;
    int* offs_src = ip;  ip += NN + 1;
    int* cur_src  = ip;  ip += NN;
    int* dsts_s   = ip;  ip += NNZ_INC;
    int* offs_e   = ip;  ip += NE + 1;
    int* cur_e    = ip;  ip += NE;
    int* offs_v   = ip;  ip += NN + 1;
    int* cur_v    = ip;  ip += NN;
    int* bsums    = ip;  ip += NB_TOT;
    ip += (((size_t)ip & 4) ? 1 : 0);          // 8B-align for int2
    int2* ev_e    = (int2*)ip; ip += 2 * NNZ_E;
    int2* ev_v    = (int2*)ip; ip += 2 * NNZ_V;

    float* out_v = (float*)d_out;     // [NN,D]
    float* out_e = out_v + ND;        // [NE,D]

    dim3 b256(256);
    int gN  = (NN + 63) / 64, gE = (NE + 63) / 64;
    int gNr = (NN + 3) / 4,  gEr = (NE + 3) / 4;
    int gNNZ = (NNZ_INC + NNZ_E + NNZ_V + 255) / 256;

    // ---- CSR build ----
    hipMemsetAsync(cnt_dst, 0, (size_t)(2 * NE + 2 * NN) * sizeof(int), stream);
    hist_all<<<gNNZ, b256, 0, stream>>>(inc_src, inc_dst, cnt_src, cnt_dst,
                                        emat_rows, cnt_e, vmat_rows, cnt_v);
    scan_partial<<<NB_TOT, b256, 0, stream>>>(cnt_dst, cnt_src, cnt_e, cnt_v, bsums);
    scan_bsums<<<1, b256, 0, stream>>>(bsums, offs_dst, offs_src, offs_e, offs_v);
    scan_final<<<NB_TOT, b256, 0, stream>>>(cnt_dst, offs_dst, cur_dst,
                                            cnt_src, offs_src, cur_src,
                                            cnt_e,   offs_e,   cur_e,
                                            cnt_v,   offs_v,   cur_v, bsums);
    fill_all<<<gNNZ, b256, 0, stream>>>(inc_src, inc_dst, cur_dst, srcs_s, cur_src, dsts_s,
                                        emat_rows, emat_cols, emat_vals, cur_e, ev_e,
                                        vmat_rows, vmat_cols, vmat_vals, cur_v, ev_v);

    // ---- psi1 path ----
    gemm128<<<gN, b256, 0, stream>>>(vfeat, psi1_W, 2 * D, nullptr, F0, NN, 0);       // Pv
    gemm128<<<gE, b256, 0, stream>>>(efeat, psi1_W + D, 2 * D, psi1_b, F3, NE, 0);    // PeP = Pe + b1
    gather_A<<<gEr, b256, 0, stream>>>(offs_dst, srcs_s, invDV, F0, F3, F4, NE);      // A
    gather_spmm<<<gEr, b256, 0, stream>>>(offs_e, ev_e, F4, efeat, F5, NE);           // A2 = emat@A + efeat
    gather_src2<<<gNr, b256, 0, stream>>>(offs_src, dsts_s, F5, efeat, F1, F2, NN);   // vf1, vf2
    gemm128<<<gN, b256, 0, stream>>>(F1, Wv, D, nullptr, out_v, NN, 1);               // vfeat_out

    // ---- psi2 + vMat path ----
    gemm128<<<gN, b256, 0, stream>>>(out_v, psi2_W, 2 * D, nullptr, F0, NN, 0);       // Qv
    gemm128<<<gE, b256, 0, stream>>>(efeat, psi2_W + D, 2 * D, psi2_b, F3, NE, 0);    // QeP = Qe + b2
    gather_spmm<<<gNr, b256, 0, stream>>>(offs_v, ev_v, F2, nullptr, F1, NN);         // vf2b = vmat@vf2
    gather_final<<<gEr, b256, 0, stream>>>(offs_dst, srcs_s, F0, F3, invDE, F1, F4, NE); // ef2
    gemm128<<<gE, b256, 0, stream>>>(F4, We, D, nullptr, out_e, NE, 1);               // efeat_out
}

// Round 6
// 480.553 us; speedup vs baseline: 3.2555x; 1.2280x over previous
//
#include <hip/hip_runtime.h>

#define NN 50000
#define NE 10000
#define NNZ_INC 400000
#define NNZ_E 80000
#define NNZ_V 400000
#define NNZ_TOT (NNZ_INC + NNZ_E + NNZ_V)
#define D 128
#define KC 32

#define GN_ 782                      // ceil(NN/64)
#define GE_ 157                      // ceil(NE/64)
#define G_FILL ((NNZ_TOT + 255) / 256)
#define G_SPMMV ((NN + 3) / 4)

#define NB_NE 5                      // ceil(10000/2048)
#define NB_NN 25                     // ceil(50000/2048)
#define NB_TOT (2*NB_NE + 2*NB_NN)   // 60

// ---------------- dense GEMM body: out[M,128] = act(X @ W[:, :128].T + b) -------------
__device__ __forceinline__ void gemm_body(
    int bx, const float* __restrict__ X, const float* __restrict__ W, int ldw,
    const float* __restrict__ bias, float* __restrict__ out, int M, int doRelu)
{
    __shared__ float XsT[KC][68];
    __shared__ float Ws[KC][132];
    const int tid = threadIdx.x;
    const int tx = tid & 31, ty = tid >> 5;
    const int row0 = bx * 64;
    const int c0 = tx * 4;
    const int r0 = ty * 8;

    float acc[8][4];
#pragma unroll
    for (int r = 0; r < 8; ++r)
#pragma unroll
        for (int c = 0; c < 4; ++c) acc[r][c] = 0.f;

    for (int kc = 0; kc < D; kc += KC) {
        __syncthreads();
#pragma unroll
        for (int it = 0; it < 2; ++it) {
            int l = tid + it * 256;
            int r = l >> 3, k4 = l & 7;
            float4 v = make_float4(0.f, 0.f, 0.f, 0.f);
            int row = row0 + r;
            if (row < M) v = ((const float4*)(X + (size_t)row * D + kc))[k4];
            int k = k4 * 4;
            XsT[k + 0][r] = v.x; XsT[k + 1][r] = v.y;
            XsT[k + 2][r] = v.z; XsT[k + 3][r] = v.w;
        }
#pragma unroll
        for (int it = 0; it < 4; ++it) {
            int l = tid + it * 256;
            int o = l >> 3, k4 = l & 7;
            float4 w = ((const float4*)(W + (size_t)o * ldw + kc))[k4];
            int k = k4 * 4;
            Ws[k + 0][o] = w.x; Ws[k + 1][o] = w.y;
            Ws[k + 2][o] = w.z; Ws[k + 3][o] = w.w;
        }
        __syncthreads();
#pragma unroll
        for (int k = 0; k < KC; ++k) {
            const float4 a0 = *(const float4*)&XsT[k][r0];
            const float4 a1 = *(const float4*)&XsT[k][r0 + 4];
            const float4 b  = *(const float4*)&Ws[k][c0];
            float av[8] = {a0.x, a0.y, a0.z, a0.w, a1.x, a1.y, a1.z, a1.w};
            float bv[4] = {b.x, b.y, b.z, b.w};
#pragma unroll
            for (int r = 0; r < 8; ++r)
#pragma unroll
                for (int c = 0; c < 4; ++c)
                    acc[r][c] = fmaf(av[r], bv[c], acc[r][c]);
        }
    }

    float4 b4 = bias ? ((const float4*)bias)[tx] : make_float4(0.f, 0.f, 0.f, 0.f);
#pragma unroll
    for (int r = 0; r < 8; ++r) {
        int row = row0 + r0 + r;
        if (row < M) {
            float4 v;
            v.x = acc[r][0] + b4.x; v.y = acc[r][1] + b4.y;
            v.z = acc[r][2] + b4.z; v.w = acc[r][3] + b4.w;
            if (doRelu) {
                v.x = fmaxf(v.x, 0.f); v.y = fmaxf(v.y, 0.f);
                v.z = fmaxf(v.z, 0.f); v.w = fmaxf(v.w, 0.f);
            }
            ((float4*)(out + (size_t)row * D))[tx] = v;
        }
    }
}

__global__ __launch_bounds__(256) void gemm128(
    const float* __restrict__ X, const float* __restrict__ W, int ldw,
    const float* __restrict__ bias, float* __restrict__ out, int M, int doRelu)
{
    gemm_body(blockIdx.x, X, W, ldw, bias, out, M, doRelu);
}

// ---------------- histograms WITH rank capture ----------------------------------------
__global__ void hist_all(const int* __restrict__ src, const int* __restrict__ dst,
                         int* __restrict__ cnt_src, int* __restrict__ cnt_dst,
                         int* __restrict__ rinc_s, int* __restrict__ rinc_d,
                         const int* __restrict__ erows, int* __restrict__ cnt_e, int* __restrict__ re,
                         const int* __restrict__ vrows, int* __restrict__ cnt_v, int* __restrict__ rv)
{
    int i = blockIdx.x * 256 + threadIdx.x;
    if (i < NNZ_INC) {
        rinc_d[i] = atomicAdd(cnt_dst + dst[i], 1);
        rinc_s[i] = atomicAdd(cnt_src + src[i], 1);
    } else if (i < NNZ_INC + NNZ_E) {
        int j = i - NNZ_INC;
        re[j] = atomicAdd(cnt_e + erows[j], 1);
    } else if (i < NNZ_TOT) {
        int j = i - NNZ_INC - NNZ_E;
        rv[j] = atomicAdd(cnt_v + vrows[j], 1);
    }
}

// ---------------- 3-phase batched scan over the 4 count arrays ------------------------
__device__ inline void scan_map(int b, const int* c0, const int* c1, const int* c2,
                                const int* c3, const int*& cnt, int& n, int& lb, int& off)
{
    if (b < NB_NE)                { cnt = c0; n = NE; lb = b;                     off = 0; }
    else if (b < NB_NE + NB_NN)   { cnt = c1; n = NN; lb = b - NB_NE;             off = NB_NE; }
    else if (b < 2*NB_NE + NB_NN) { cnt = c2; n = NE; lb = b - NB_NE - NB_NN;     off = NB_NE + NB_NN; }
    else                          { cnt = c3; n = NN; lb = b - 2*NB_NE - NB_NN;   off = 2*NB_NE + NB_NN; }
}

__global__ __launch_bounds__(256) void scan_partial(
    const int* __restrict__ c0, const int* __restrict__ c1,
    const int* __restrict__ c2, const int* __restrict__ c3, int* __restrict__ bsums)
{
    __shared__ int wsum[4];
    const int* cnt; int n, lb, off;
    scan_map(blockIdx.x, c0, c1, c2, c3, cnt, n, lb, off);
    int lane = threadIdx.x & 63, wid = threadIdx.x >> 6;
    int i0 = lb * 2048 + threadIdx.x * 8;
    int s = 0;
#pragma unroll
    for (int k = 0; k < 8; ++k) {
        int i = i0 + k;
        if (i < n) s += cnt[i];
    }
#pragma unroll
    for (int d = 1; d < 64; d <<= 1) s += __shfl_xor(s, d, 64);
    if (lane == 0) wsum[wid] = s;
    __syncthreads();
    if (threadIdx.x == 0) bsums[off + lb] = wsum[0] + wsum[1] + wsum[2] + wsum[3];
}

__global__ __launch_bounds__(256) void scan_bsums(
    int* __restrict__ bsums, int* o0, int* o1, int* o2, int* o3)
{
    int wid = threadIdx.x >> 6, lane = threadIdx.x & 63;
    int st, nb, n; int* offs;
    switch (wid) {
        case 0:  st = 0;               nb = NB_NE; n = NE; offs = o0; break;
        case 1:  st = NB_NE;           nb = NB_NN; n = NN; offs = o1; break;
        case 2:  st = NB_NE + NB_NN;   nb = NB_NE; n = NE; offs = o2; break;
        default: st = 2*NB_NE + NB_NN; nb = NB_NN; n = NN; offs = o3; break;
    }
    int v = (lane < nb) ? bsums[st + lane] : 0;
    int incl = v;
#pragma unroll
    for (int s = 1; s < 64; s <<= 1) {
        int t = __shfl_up(incl, s, 64);
        if (lane >= s) incl += t;
    }
    if (lane < nb) bsums[st + lane] = incl - v;
    if (lane == 63) offs[n] = incl;
}

__global__ __launch_bounds__(256) void scan_final(
    const int* __restrict__ c0, int* __restrict__ o0,
    const int* __restrict__ c1, int* __restrict__ o1,
    const int* __restrict__ c2, int* __restrict__ o2,
    const int* __restrict__ c3, int* __restrict__ o3,
    const int* __restrict__ bsums)
{
    __shared__ int wsum[4];
    const int* cnt; int n, lb, off;
    scan_map(blockIdx.x, c0, c1, c2, c3, cnt, n, lb, off);
    int* offs;
    int b = blockIdx.x;
    if (b < NB_NE)                offs = o0;
    else if (b < NB_NE + NB_NN)   offs = o1;
    else if (b < 2*NB_NE + NB_NN) offs = o2;
    else                          offs = o3;
    int base = bsums[off + lb];
    int lane = threadIdx.x & 63, wid = threadIdx.x >> 6;
    int i0 = lb * 2048 + threadIdx.x * 8;
    int v[8]; int tsum = 0;
#pragma unroll
    for (int k = 0; k < 8; ++k) {
        int i = i0 + k;
        v[k] = (i < n) ? cnt[i] : 0;
        tsum += v[k];
    }
    int incl = tsum;
#pragma unroll
    for (int s = 1; s < 64; s <<= 1) {
        int t = __shfl_up(incl, s, 64);
        if (lane >= s) incl += t;
    }
    if (lane == 63) wsum[wid] = incl;
    __syncthreads();
    int woff = 0;
    for (int w = 0; w < wid; ++w) woff += wsum[w];
    int run = base + woff + incl - tsum;
#pragma unroll
    for (int k = 0; k < 8; ++k) {
        int i = i0 + k;
        if (i < n) offs[i] = run;
        run += v[k];
    }
}

// ---------------- atomic-free fill body (positions from offs + precomputed rank) ------
__device__ __forceinline__ void fill_body(int fb,
    const int* __restrict__ src, const int* __restrict__ dst,
    const int* __restrict__ rinc_d, const int* __restrict__ rinc_s,
    const int* __restrict__ offs_dst, const int* __restrict__ offs_src,
    int* __restrict__ srcs_s, int* __restrict__ dsts_s,
    const int* __restrict__ erows, const int* __restrict__ ecols,
    const float* __restrict__ evals, const int* __restrict__ re,
    const int* __restrict__ offs_e, int2* __restrict__ ev_e,
    const int* __restrict__ vrows, const int* __restrict__ vcols,
    const float* __restrict__ vvals, const int* __restrict__ rv,
    const int* __restrict__ offs_v, int2* __restrict__ ev_v)
{
    int i = fb * 256 + threadIdx.x;
    if (i < NNZ_INC) {
        int s = src[i], d = dst[i];
        srcs_s[offs_dst[d] + rinc_d[i]] = s;
        dsts_s[offs_src[s] + rinc_s[i]] = d;
    } else if (i < NNZ_INC + NNZ_E) {
        int j = i - NNZ_INC;
        ev_e[offs_e[erows[j]] + re[j]] = make_int2(ecols[j], __float_as_int(evals[j]));
    } else if (i < NNZ_TOT) {
        int j = i - NNZ_INC - NNZ_E;
        ev_v[offs_v[vrows[j]] + rv[j]] = make_int2(vcols[j], __float_as_int(vvals[j]));
    }
}

// ---------------- fused1: gemm Pv | gemm PeP | gemm QeP | fill ------------------------
__global__ __launch_bounds__(256) void fused1(
    const float* __restrict__ vfeat, const float* __restrict__ efeat,
    const float* __restrict__ psi1_W, const float* __restrict__ psi1_b,
    const float* __restrict__ psi2_W, const float* __restrict__ psi2_b,
    float* __restrict__ Pv, float* __restrict__ PeP, float* __restrict__ QeP,
    const int* __restrict__ src, const int* __restrict__ dst,
    const int* __restrict__ rinc_d, const int* __restrict__ rinc_s,
    const int* __restrict__ offs_dst, const int* __restrict__ offs_src,
    int* __restrict__ srcs_s, int* __restrict__ dsts_s,
    const int* __restrict__ erows, const int* __restrict__ ecols,
    const float* __restrict__ evals, const int* __restrict__ re,
    const int* __restrict__ offs_e, int2* __restrict__ ev_e,
    const int* __restrict__ vrows, const int* __restrict__ vcols,
    const float* __restrict__ vvals, const int* __restrict__ rv,
    const int* __restrict__ offs_v, int2* __restrict__ ev_v)
{
    int b = blockIdx.x;
    if (b < GN_) {
        gemm_body(b, vfeat, psi1_W, 2 * D, nullptr, Pv, NN, 0);
    } else if (b < GN_ + GE_) {
        gemm_body(b - GN_, efeat, psi1_W + D, 2 * D, psi1_b, PeP, NE, 0);
    } else if (b < GN_ + 2 * GE_) {
        gemm_body(b - GN_ - GE_, efeat, psi2_W + D, 2 * D, psi2_b, QeP, NE, 0);
    } else {
        fill_body(b - GN_ - 2 * GE_, src, dst, rinc_d, rinc_s, offs_dst, offs_src,
                  srcs_s, dsts_s, erows, ecols, evals, re, offs_e, ev_e,
                  vrows, vcols, vvals, rv, offs_v, ev_v);
    }
}

// ---------------- A[e,:] = sum_s invDV[s]*Pv[s,:] + (sum_s invDV[s])*PeP[e,:] --------
__global__ __launch_bounds__(256) void gather_A(
    const int* __restrict__ offs, const int* __restrict__ srcs,
    const float* __restrict__ invDV, const float* __restrict__ Pv,
    const float* __restrict__ PeP, float* __restrict__ A, int E)
{
    int e = blockIdx.x * 4 + (threadIdx.x >> 6);
    int l = threadIdx.x & 63;
    if (e >= E) return;
    int j0 = offs[e], j1 = offs[e + 1];
    float2 acc = make_float2(0.f, 0.f);
    float wsum = 0.f;
    int j = j0;
    for (; j + 3 < j1; j += 4) {
        int s0 = srcs[j], s1 = srcs[j + 1], s2 = srcs[j + 2], s3 = srcs[j + 3];
        float w0 = invDV[s0], w1 = invDV[s1], w2 = invDV[s2], w3 = invDV[s3];
        float2 p0 = ((const float2*)(Pv + (size_t)s0 * D))[l];
        float2 p1 = ((const float2*)(Pv + (size_t)s1 * D))[l];
        float2 p2 = ((const float2*)(Pv + (size_t)s2 * D))[l];
        float2 p3 = ((const float2*)(Pv + (size_t)s3 * D))[l];
        wsum += w0 + w1 + w2 + w3;
        acc.x = fmaf(w0, p0.x, fmaf(w1, p1.x, fmaf(w2, p2.x, fmaf(w3, p3.x, acc.x))));
        acc.y = fmaf(w0, p0.y, fmaf(w1, p1.y, fmaf(w2, p2.y, fmaf(w3, p3.y, acc.y))));
    }
    for (; j < j1; ++j) {
        int s = srcs[j];
        float w = invDV[s];
        float2 p = ((const float2*)(Pv + (size_t)s * D))[l];
        wsum += w;
        acc.x = fmaf(w, p.x, acc.x);
        acc.y = fmaf(w, p.y, acc.y);
    }
    float2 pe = ((const float2*)(PeP + (size_t)e * D))[l];
    acc.x = fmaf(wsum, pe.x, acc.x);
    acc.y = fmaf(wsum, pe.y, acc.y);
    ((float2*)(A + (size_t)e * D))[l] = acc;
}

// -------- spmm body: Y[r,:] = (addend?addend[r,:]:0) + sum_j val_j * X[col_j,:] ------
__device__ __forceinline__ void spmm_body(int rb,
    const int* __restrict__ offs, const int2* __restrict__ ev,
    const float* __restrict__ X, const float* __restrict__ addend,
    float* __restrict__ Y, int R)
{
    int r = rb * 4 + (threadIdx.x >> 6);
    int l = threadIdx.x & 63;
    if (r >= R) return;
    int j0 = offs[r], j1 = offs[r + 1];
    float2 acc = addend ? ((const float2*)(addend + (size_t)r * D))[l]
                        : make_float2(0.f, 0.f);
    int j = j0;
    for (; j + 3 < j1; j += 4) {
        int2 e0 = ev[j], e1 = ev[j + 1], e2 = ev[j + 2], e3 = ev[j + 3];
        float2 x0 = ((const float2*)(X + (size_t)e0.x * D))[l];
        float2 x1 = ((const float2*)(X + (size_t)e1.x * D))[l];
        float2 x2 = ((const float2*)(X + (size_t)e2.x * D))[l];
        float2 x3 = ((const float2*)(X + (size_t)e3.x * D))[l];
        float v0 = __int_as_float(e0.y), v1 = __int_as_float(e1.y);
        float v2 = __int_as_float(e2.y), v3 = __int_as_float(e3.y);
        acc.x = fmaf(v0, x0.x, fmaf(v1, x1.x, fmaf(v2, x2.x, fmaf(v3, x3.x, acc.x))));
        acc.y = fmaf(v0, x0.y, fmaf(v1, x1.y, fmaf(v2, x2.y, fmaf(v3, x3.y, acc.y))));
    }
    for (; j < j1; ++j) {
        int2 e = ev[j];
        float2 x = ((const float2*)(X + (size_t)e.x * D))[l];
        float v = __int_as_float(e.y);
        acc.x = fmaf(v, x.x, acc.x);
        acc.y = fmaf(v, x.y, acc.y);
    }
    ((float2*)(Y + (size_t)r * D))[l] = acc;
}

__global__ __launch_bounds__(256) void gather_spmm(
    const int* __restrict__ offs, const int2* __restrict__ ev,
    const float* __restrict__ X, const float* __restrict__ addend,
    float* __restrict__ Y, int R)
{
    spmm_body(blockIdx.x, offs, ev, X, addend, Y, R);
}

// ---------------- fused2: gemm Qv | vmat spmm -----------------------------------------
__global__ __launch_bounds__(256) void fused2(
    const float* __restrict__ out_v, const float* __restrict__ psi2_W,
    float* __restrict__ Qv,
    const int* __restrict__ offs_v, const int2* __restrict__ ev_v,
    const float* __restrict__ vf2, float* __restrict__ vf2b)
{
    int b = blockIdx.x;
    if (b < GN_) gemm_body(b, out_v, psi2_W, 2 * D, nullptr, Qv, NN, 0);
    else spmm_body(b - GN_, offs_v, ev_v, vf2, nullptr, vf2b, NN);
}

// ---------------- vf1[n,:] = sum_d ef1[d,:]; vf2[n,:] = sum_d ef0[d,:] ---------------
__global__ __launch_bounds__(256) void gather_src2(
    const int* __restrict__ offs, const int* __restrict__ dsts,
    const float* __restrict__ ef1, const float* __restrict__ ef0,
    float* __restrict__ vf1, float* __restrict__ vf2, int N)
{
    int n = blockIdx.x * 4 + (threadIdx.x >> 6);
    int l = threadIdx.x & 63;
    if (n >= N) return;
    int j0 = offs[n], j1 = offs[n + 1];
    float2 a1 = make_float2(0.f, 0.f), a2 = make_float2(0.f, 0.f);
    int j = j0;
    for (; j + 3 < j1; j += 4) {
        int d0 = dsts[j], d1 = dsts[j + 1], d2 = dsts[j + 2], d3 = dsts[j + 3];
        float2 p0 = ((const float2*)(ef1 + (size_t)d0 * D))[l];
        float2 p1 = ((const float2*)(ef1 + (size_t)d1 * D))[l];
        float2 p2 = ((const float2*)(ef1 + (size_t)d2 * D))[l];
        float2 p3 = ((const float2*)(ef1 + (size_t)d3 * D))[l];
        float2 q0 = ((const float2*)(ef0 + (size_t)d0 * D))[l];
        float2 q1 = ((const float2*)(ef0 + (size_t)d1 * D))[l];
        float2 q2 = ((const float2*)(ef0 + (size_t)d2 * D))[l];
        float2 q3 = ((const float2*)(ef0 + (size_t)d3 * D))[l];
        a1.x += (p0.x + p1.x) + (p2.x + p3.x);
        a1.y += (p0.y + p1.y) + (p2.y + p3.y);
        a2.x += (q0.x + q1.x) + (q2.x + q3.x);
        a2.y += (q0.y + q1.y) + (q2.y + q3.y);
    }
    for (; j < j1; ++j) {
        int d = dsts[j];
        float2 x1 = ((const float2*)(ef1 + (size_t)d * D))[l];
        float2 x0 = ((const float2*)(ef0 + (size_t)d * D))[l];
        a1.x += x1.x; a1.y += x1.y;
        a2.x += x0.x; a2.y += x0.y;
    }
    ((float2*)(vf1 + (size_t)n * D))[l] = a1;
    ((float2*)(vf2 + (size_t)n * D))[l] = a2;
}

// ------- ef2[e,:] = (sum_s Qv[s,:] + deg[e]*QeP[e,:]) * invDE[e] + sum_s vf2b[s,:] ---
__global__ __launch_bounds__(256) void gather_final(
    const int* __restrict__ offs, const int* __restrict__ srcs,
    const float* __restrict__ Qv, const float* __restrict__ QeP,
    const float* __restrict__ invDE, const float* __restrict__ vf2b,
    float* __restrict__ ef2, int E)
{
    int e = blockIdx.x * 4 + (threadIdx.x >> 6);
    int l = threadIdx.x & 63;
    if (e >= E) return;
    int j0 = offs[e], j1 = offs[e + 1];
    float deg = (float)(j1 - j0);
    float2 aq = make_float2(0.f, 0.f), av = make_float2(0.f, 0.f);
    int j = j0;
    for (; j + 3 < j1; j += 4) {
        int s0 = srcs[j], s1 = srcs[j + 1], s2 = srcs[j + 2], s3 = srcs[j + 3];
        float2 q0 = ((const float2*)(Qv + (size_t)s0 * D))[l];
        float2 q1 = ((const float2*)(Qv + (size_t)s1 * D))[l];
        float2 q2 = ((const float2*)(Qv + (size_t)s2 * D))[l];
        float2 q3 = ((const float2*)(Qv + (size_t)s3 * D))[l];
        float2 v0 = ((const float2*)(vf2b + (size_t)s0 * D))[l];
        float2 v1 = ((const float2*)(vf2b + (size_t)s1 * D))[l];
        float2 v2 = ((const float2*)(vf2b + (size_t)s2 * D))[l];
        float2 v3 = ((const float2*)(vf2b + (size_t)s3 * D))[l];
        aq.x += (q0.x + q1.x) + (q2.x + q3.x);
        aq.y += (q0.y + q1.y) + (q2.y + q3.y);
        av.x += (v0.x + v1.x) + (v2.x + v3.x);
        av.y += (v0.y + v1.y) + (v2.y + v3.y);
    }
    for (; j < j1; ++j) {
        int s = srcs[j];
        float2 q = ((const float2*)(Qv + (size_t)s * D))[l];
        float2 v = ((const float2*)(vf2b + (size_t)s * D))[l];
        aq.x += q.x; aq.y += q.y;
        av.x += v.x; av.y += v.y;
    }
    float2 qe = ((const float2*)(QeP + (size_t)e * D))[l];
    float ide = invDE[e];
    float2 out;
    out.x = fmaf(deg, qe.x, aq.x) * ide + av.x;
    out.y = fmaf(deg, qe.y, aq.y) * ide + av.y;
    ((float2*)(ef2 + (size_t)e * D))[l] = out;
}

extern "C" void kernel_launch(void* const* d_in, const int* in_sizes, int n_in,
                              void* d_out, int out_size, void* d_ws, size_t ws_size,
                              hipStream_t stream)
{
    (void)in_sizes; (void)n_in; (void)out_size; (void)ws_size;
    const float* vfeat     = (const float*)d_in[0];
    const float* efeat     = (const float*)d_in[1];
    const float* invDV     = (const float*)d_in[2];
    const float* invDE     = (const float*)d_in[3];
    const int*   inc_src   = (const int*)d_in[4];
    const int*   inc_dst   = (const int*)d_in[5];
    const int*   emat_rows = (const int*)d_in[6];
    const int*   emat_cols = (const int*)d_in[7];
    const float* emat_vals = (const float*)d_in[8];
    const int*   vmat_rows = (const int*)d_in[9];
    const int*   vmat_cols = (const int*)d_in[10];
    const float* vmat_vals = (const float*)d_in[11];
    const float* Wv        = (const float*)d_in[12];
    const float* We        = (const float*)d_in[13];
    const float* psi1_W    = (const float*)d_in[14];
    const float* psi1_b    = (const float*)d_in[15];
    const float* psi2_W    = (const float*)d_in[16];
    const float* psi2_b    = (const float*)d_in[17];

    const size_t ND = (size_t)NN * D;
    const size_t ED = (size_t)NE * D;

    float* F0 = (float*)d_ws;    // Pv -> Qv            [NN,D]
    float* F1 = F0 + ND;         // vf1 -> vf2b         [NN,D]
    float* F2 = F1 + ND;         // vf2                 [NN,D]
    float* F3 = F2 + ND;         // PeP                 [NE,D]
    float* F4 = F3 + ED;         // A -> ef2            [NE,D]
    float* F5 = F4 + ED;         // A2 (_efeat)         [NE,D]
    float* F6 = F5 + ED;         // QeP                 [NE,D]

    int* ip       = (int*)(F6 + ED);
    int* cnt_dst  = ip;  ip += NE;       // contiguous counts block for one memset
    int* cnt_src  = ip;  ip += NN;
    int* cnt_e    = ip;  ip += NE;
    int* cnt_v    = ip;  ip += NN;
    int* offs_dst = ip;  ip += NE + 1;
    int* offs_src = ip;  ip += NN + 1;
    int* offs_e   = ip;  ip += NE + 1;
    int* offs_v   = ip;  ip += NN + 1;
    int* rinc_d   = ip;  ip += NNZ_INC;
    int* rinc_s   = ip;  ip += NNZ_INC;
    int* re       = ip;  ip += NNZ_E;
    int* rv       = ip;  ip += NNZ_V;
    int* srcs_s   = ip;  ip += NNZ_INC;
    int* dsts_s   = ip;  ip += NNZ_INC;
    int* bsums    = ip;  ip += NB_TOT;
    ip += (((size_t)ip & 4) ? 1 : 0);          // 8B-align for int2
    int2* ev_e    = (int2*)ip; ip += 2 * NNZ_E;
    int2* ev_v    = (int2*)ip; ip += 2 * NNZ_V;

    float* out_v = (float*)d_out;     // [NN,D]
    float* out_e = out_v + ND;        // [NE,D]

    dim3 b256(256);
    int gNr = (NN + 3) / 4, gEr = (NE + 3) / 4;

    // ---- CSR build (ranks captured in hist; scan produces offs; fill is atomic-free) -
    hipMemsetAsync(cnt_dst, 0, (size_t)(2 * NE + 2 * NN) * sizeof(int), stream);
    hist_all<<<G_FILL, b256, 0, stream>>>(inc_src, inc_dst, cnt_src, cnt_dst,
                                          rinc_s, rinc_d,
                                          emat_rows, cnt_e, re,
                                          vmat_rows, cnt_v, rv);
    scan_partial<<<NB_TOT, b256, 0, stream>>>(cnt_dst, cnt_src, cnt_e, cnt_v, bsums);
    scan_bsums<<<1, b256, 0, stream>>>(bsums, offs_dst, offs_src, offs_e, offs_v);
    scan_final<<<NB_TOT, b256, 0, stream>>>(cnt_dst, offs_dst, cnt_src, offs_src,
                                            cnt_e, offs_e, cnt_v, offs_v, bsums);

    // ---- fused1: Pv | PeP | QeP gemms overlap with fill ----
    fused1<<<GN_ + 2 * GE_ + G_FILL, b256, 0, stream>>>(
        vfeat, efeat, psi1_W, psi1_b, psi2_W, psi2_b, F0, F3, F6,
        inc_src, inc_dst, rinc_d, rinc_s, offs_dst, offs_src, srcs_s, dsts_s,
        emat_rows, emat_cols, emat_vals, re, offs_e, ev_e,
        vmat_rows, vmat_cols, vmat_vals, rv, offs_v, ev_v);

    // ---- psi1 path ----
    gather_A<<<gEr, b256, 0, stream>>>(offs_dst, srcs_s, invDV, F0, F3, F4, NE);      // A
    gather_spmm<<<gEr, b256, 0, stream>>>(offs_e, ev_e, F4, efeat, F5, NE);           // A2 = emat@A + efeat
    gather_src2<<<gNr, b256, 0, stream>>>(offs_src, dsts_s, F5, efeat, F1, F2, NN);   // vf1, vf2
    gemm128<<<GN_, b256, 0, stream>>>(F1, Wv, D, nullptr, out_v, NN, 1);              // vfeat_out

    // ---- fused2: Qv gemm overlaps with vmat spmm (vf2b -> F1, vf1 dead) ----
    fused2<<<GN_ + G_SPMMV, b256, 0, stream>>>(out_v, psi2_W, F0, offs_v, ev_v, F2, F1);

    gather_final<<<gEr, b256, 0, stream>>>(offs_dst, srcs_s, F0, F6, invDE, F1, F4, NE); // ef2
    gemm128<<<GE_, b256, 0, stream>>>(F4, We, D, nullptr, out_e, NE, 1);              // efeat_out
}

// Round 7
// 439.615 us; speedup vs baseline: 3.5587x; 1.0931x over previous
//
#include <hip/hip_runtime.h>

#define NN 50000
#define NE 10000
#define NNZ_INC 400000
#define NNZ_E 80000
#define NNZ_V 400000
#define NNZ_TOT (NNZ_INC + NNZ_E + NNZ_V)
#define D 128
#define KC 32

#define GN_ 782                      // ceil(NN/64)
#define GE_ 157                      // ceil(NE/64)
#define G_FILL ((NNZ_TOT + 255) / 256)   // 3438
#define G_CVT 1250                   // NE*D / (256*4)
#define GNR ((NN + 3) / 4)           // 12500
#define GER ((NE + 3) / 4)           // 2500

#define NB_NE 5
#define NB_NN 25
#define NB_TOT (2*NB_NE + 2*NB_NN)   // 60

typedef unsigned short u16;

__device__ __forceinline__ u16 f2bf(float x) {
    unsigned u = __float_as_uint(x);
    unsigned r = u + 0x7fffu + ((u >> 16) & 1u);
    return (u16)(r >> 16);
}
__device__ __forceinline__ float bf2f(u16 h) {
    return __uint_as_float(((unsigned)h) << 16);
}
__device__ __forceinline__ float2 ldbf2(const u16* rowbase, int l) {
    ushort2 t = ((const ushort2*)rowbase)[l];
    return make_float2(bf2f(t.x), bf2f(t.y));
}

// ---------------- dense GEMM body: out[M,128] = act(X @ W[:, :128].T + b) -------------
// mode: 0 = fp32, 1 = fp32 + relu, 2 = bf16 (no relu)
__device__ __forceinline__ void gemm_body(
    int bx, const float* __restrict__ X, const float* __restrict__ W, int ldw,
    const float* __restrict__ bias, void* __restrict__ out, int M, int mode)
{
    __shared__ float XsT[KC][68];
    __shared__ float Ws[KC][132];
    const int tid = threadIdx.x;
    const int tx = tid & 31, ty = tid >> 5;
    const int row0 = bx * 64;
    const int c0 = tx * 4;
    const int r0 = ty * 8;

    float acc[8][4];
#pragma unroll
    for (int r = 0; r < 8; ++r)
#pragma unroll
        for (int c = 0; c < 4; ++c) acc[r][c] = 0.f;

    for (int kc = 0; kc < D; kc += KC) {
        __syncthreads();
#pragma unroll
        for (int it = 0; it < 2; ++it) {
            int l = tid + it * 256;
            int r = l >> 3, k4 = l & 7;
            float4 v = make_float4(0.f, 0.f, 0.f, 0.f);
            int row = row0 + r;
            if (row < M) v = ((const float4*)(X + (size_t)row * D + kc))[k4];
            int k = k4 * 4;
            XsT[k + 0][r] = v.x; XsT[k + 1][r] = v.y;
            XsT[k + 2][r] = v.z; XsT[k + 3][r] = v.w;
        }
#pragma unroll
        for (int it = 0; it < 4; ++it) {
            int l = tid + it * 256;
            int o = l >> 3, k4 = l & 7;
            float4 w = ((const float4*)(W + (size_t)o * ldw + kc))[k4];
            int k = k4 * 4;
            Ws[k + 0][o] = w.x; Ws[k + 1][o] = w.y;
            Ws[k + 2][o] = w.z; Ws[k + 3][o] = w.w;
        }
        __syncthreads();
#pragma unroll
        for (int k = 0; k < KC; ++k) {
            const float4 a0 = *(const float4*)&XsT[k][r0];
            const float4 a1 = *(const float4*)&XsT[k][r0 + 4];
            const float4 b  = *(const float4*)&Ws[k][c0];
            float av[8] = {a0.x, a0.y, a0.z, a0.w, a1.x, a1.y, a1.z, a1.w};
            float bv[4] = {b.x, b.y, b.z, b.w};
#pragma unroll
            for (int r = 0; r < 8; ++r)
#pragma unroll
                for (int c = 0; c < 4; ++c)
                    acc[r][c] = fmaf(av[r], bv[c], acc[r][c]);
        }
    }

    float4 b4 = bias ? ((const float4*)bias)[tx] : make_float4(0.f, 0.f, 0.f, 0.f);
#pragma unroll
    for (int r = 0; r < 8; ++r) {
        int row = row0 + r0 + r;
        if (row < M) {
            float vx = acc[r][0] + b4.x, vy = acc[r][1] + b4.y;
            float vz = acc[r][2] + b4.z, vw = acc[r][3] + b4.w;
            if (mode == 1) {
                vx = fmaxf(vx, 0.f); vy = fmaxf(vy, 0.f);
                vz = fmaxf(vz, 0.f); vw = fmaxf(vw, 0.f);
            }
            if (mode == 2) {
                ushort4 u;
                u.x = f2bf(vx); u.y = f2bf(vy); u.z = f2bf(vz); u.w = f2bf(vw);
                ((ushort4*)((u16*)out + (size_t)row * D))[tx] = u;
            } else {
                float4 v = make_float4(vx, vy, vz, vw);
                ((float4*)((float*)out + (size_t)row * D))[tx] = v;
            }
        }
    }
}

__global__ __launch_bounds__(256) void gemm128(
    const float* __restrict__ X, const float* __restrict__ W, int ldw,
    const float* __restrict__ bias, void* __restrict__ out, int M, int mode)
{
    gemm_body(blockIdx.x, X, W, ldw, bias, out, M, mode);
}

// ---------------- histogram body WITH rank capture ------------------------------------
__device__ __forceinline__ void hist_body(int fb,
    const int* __restrict__ src, const int* __restrict__ dst,
    int* __restrict__ cnt_src, int* __restrict__ cnt_dst,
    int* __restrict__ rinc_s, int* __restrict__ rinc_d,
    const int* __restrict__ erows, int* __restrict__ cnt_e, int* __restrict__ re,
    const int* __restrict__ vrows, int* __restrict__ cnt_v, int* __restrict__ rv)
{
    int i = fb * 256 + threadIdx.x;
    if (i < NNZ_INC) {
        rinc_d[i] = atomicAdd(cnt_dst + dst[i], 1);
        rinc_s[i] = atomicAdd(cnt_src + src[i], 1);
    } else if (i < NNZ_INC + NNZ_E) {
        int j = i - NNZ_INC;
        re[j] = atomicAdd(cnt_e + erows[j], 1);
    } else if (i < NNZ_TOT) {
        int j = i - NNZ_INC - NNZ_E;
        rv[j] = atomicAdd(cnt_v + vrows[j], 1);
    }
}

// ---------------- fused0: hist | gemm PeP | gemm QeP | efeat->bf16 --------------------
__global__ __launch_bounds__(256) void fused0(
    const int* __restrict__ inc_src, const int* __restrict__ inc_dst,
    int* __restrict__ cnt_src, int* __restrict__ cnt_dst,
    int* __restrict__ rinc_s, int* __restrict__ rinc_d,
    const int* __restrict__ erows, int* __restrict__ cnt_e, int* __restrict__ re,
    const int* __restrict__ vrows, int* __restrict__ cnt_v, int* __restrict__ rv,
    const float* __restrict__ efeat,
    const float* __restrict__ psi1_W, const float* __restrict__ psi1_b, float* __restrict__ PeP,
    const float* __restrict__ psi2_W, const float* __restrict__ psi2_b, float* __restrict__ QeP,
    u16* __restrict__ efeat_b)
{
    int b = blockIdx.x;
    if (b < G_FILL) {
        hist_body(b, inc_src, inc_dst, cnt_src, cnt_dst, rinc_s, rinc_d,
                  erows, cnt_e, re, vrows, cnt_v, rv);
    } else if (b < G_FILL + GE_) {
        gemm_body(b - G_FILL, efeat, psi1_W + D, 2 * D, psi1_b, PeP, NE, 0);
    } else if (b < G_FILL + 2 * GE_) {
        gemm_body(b - G_FILL - GE_, efeat, psi2_W + D, 2 * D, psi2_b, QeP, NE, 0);
    } else {
        int i = ((b - G_FILL - 2 * GE_) * 256 + threadIdx.x) * 4;
        if (i < NE * D) {
            float4 v = *(const float4*)(efeat + i);
            ushort4 u;
            u.x = f2bf(v.x); u.y = f2bf(v.y); u.z = f2bf(v.z); u.w = f2bf(v.w);
            *(ushort4*)(efeat_b + i) = u;
        }
    }
}

// ---------------- 3-phase batched scan ------------------------------------------------
__device__ inline void scan_map(int b, const int* c0, const int* c1, const int* c2,
                                const int* c3, const int*& cnt, int& n, int& lb, int& off)
{
    if (b < NB_NE)                { cnt = c0; n = NE; lb = b;                     off = 0; }
    else if (b < NB_NE + NB_NN)   { cnt = c1; n = NN; lb = b - NB_NE;             off = NB_NE; }
    else if (b < 2*NB_NE + NB_NN) { cnt = c2; n = NE; lb = b - NB_NE - NB_NN;     off = NB_NE + NB_NN; }
    else                          { cnt = c3; n = NN; lb = b - 2*NB_NE - NB_NN;   off = 2*NB_NE + NB_NN; }
}

__global__ __launch_bounds__(256) void scan_partial(
    const int* __restrict__ c0, const int* __restrict__ c1,
    const int* __restrict__ c2, const int* __restrict__ c3, int* __restrict__ bsums)
{
    __shared__ int wsum[4];
    const int* cnt; int n, lb, off;
    scan_map(blockIdx.x, c0, c1, c2, c3, cnt, n, lb, off);
    int lane = threadIdx.x & 63, wid = threadIdx.x >> 6;
    int i0 = lb * 2048 + threadIdx.x * 8;
    int s = 0;
#pragma unroll
    for (int k = 0; k < 8; ++k) {
        int i = i0 + k;
        if (i < n) s += cnt[i];
    }
#pragma unroll
    for (int d = 1; d < 64; d <<= 1) s += __shfl_xor(s, d, 64);
    if (lane == 0) wsum[wid] = s;
    __syncthreads();
    if (threadIdx.x == 0) bsums[off + lb] = wsum[0] + wsum[1] + wsum[2] + wsum[3];
}

__global__ __launch_bounds__(256) void scan_bsums(
    int* __restrict__ bsums, int* o0, int* o1, int* o2, int* o3)
{
    int wid = threadIdx.x >> 6, lane = threadIdx.x & 63;
    int st, nb, n; int* offs;
    switch (wid) {
        case 0:  st = 0;               nb = NB_NE; n = NE; offs = o0; break;
        case 1:  st = NB_NE;           nb = NB_NN; n = NN; offs = o1; break;
        case 2:  st = NB_NE + NB_NN;   nb = NB_NE; n = NE; offs = o2; break;
        default: st = 2*NB_NE + NB_NN; nb = NB_NN; n = NN; offs = o3; break;
    }
    int v = (lane < nb) ? bsums[st + lane] : 0;
    int incl = v;
#pragma unroll
    for (int s = 1; s < 64; s <<= 1) {
        int t = __shfl_up(incl, s, 64);
        if (lane >= s) incl += t;
    }
    if (lane < nb) bsums[st + lane] = incl - v;
    if (lane == 63) offs[n] = incl;
}

__global__ __launch_bounds__(256) void scan_final(
    const int* __restrict__ c0, int* __restrict__ o0,
    const int* __restrict__ c1, int* __restrict__ o1,
    const int* __restrict__ c2, int* __restrict__ o2,
    const int* __restrict__ c3, int* __restrict__ o3,
    const int* __restrict__ bsums)
{
    __shared__ int wsum[4];
    const int* cnt; int n, lb, off;
    scan_map(blockIdx.x, c0, c1, c2, c3, cnt, n, lb, off);
    int* offs;
    int b = blockIdx.x;
    if (b < NB_NE)                offs = o0;
    else if (b < NB_NE + NB_NN)   offs = o1;
    else if (b < 2*NB_NE + NB_NN) offs = o2;
    else                          offs = o3;
    int base = bsums[off + lb];
    int lane = threadIdx.x & 63, wid = threadIdx.x >> 6;
    int i0 = lb * 2048 + threadIdx.x * 8;
    int v[8]; int tsum = 0;
#pragma unroll
    for (int k = 0; k < 8; ++k) {
        int i = i0 + k;
        v[k] = (i < n) ? cnt[i] : 0;
        tsum += v[k];
    }
    int incl = tsum;
#pragma unroll
    for (int s = 1; s < 64; s <<= 1) {
        int t = __shfl_up(incl, s, 64);
        if (lane >= s) incl += t;
    }
    if (lane == 63) wsum[wid] = incl;
    __syncthreads();
    int woff = 0;
    for (int w = 0; w < wid; ++w) woff += wsum[w];
    int run = base + woff + incl - tsum;
#pragma unroll
    for (int k = 0; k < 8; ++k) {
        int i = i0 + k;
        if (i < n) offs[i] = run;
        run += v[k];
    }
}

// ---------------- atomic-free fill body ----------------------------------------------
__device__ __forceinline__ void fill_body(int fb,
    const int* __restrict__ src, const int* __restrict__ dst,
    const int* __restrict__ rinc_d, const int* __restrict__ rinc_s,
    const int* __restrict__ offs_dst, const int* __restrict__ offs_src,
    int* __restrict__ srcs_s, int* __restrict__ dsts_s,
    const int* __restrict__ erows, const int* __restrict__ ecols,
    const float* __restrict__ evals, const int* __restrict__ re,
    const int* __restrict__ offs_e, int2* __restrict__ ev_e,
    const int* __restrict__ vrows, const int* __restrict__ vcols,
    const float* __restrict__ vvals, const int* __restrict__ rv,
    const int* __restrict__ offs_v, int2* __restrict__ ev_v)
{
    int i = fb * 256 + threadIdx.x;
    if (i < NNZ_INC) {
        int s = src[i], d = dst[i];
        srcs_s[offs_dst[d] + rinc_d[i]] = s;
        dsts_s[offs_src[s] + rinc_s[i]] = d;
    } else if (i < NNZ_INC + NNZ_E) {
        int j = i - NNZ_INC;
        ev_e[offs_e[erows[j]] + re[j]] = make_int2(ecols[j], __float_as_int(evals[j]));
    } else if (i < NNZ_TOT) {
        int j = i - NNZ_INC - NNZ_E;
        ev_v[offs_v[vrows[j]] + rv[j]] = make_int2(vcols[j], __float_as_int(vvals[j]));
    }
}

// ---------------- fusedF: gemm Pv (bf16 out) | fill ----------------------------------
__global__ __launch_bounds__(256) void fusedF(
    const float* __restrict__ vfeat, const float* __restrict__ psi1_W, u16* __restrict__ Pv_b,
    const int* __restrict__ src, const int* __restrict__ dst,
    const int* __restrict__ rinc_d, const int* __restrict__ rinc_s,
    const int* __restrict__ offs_dst, const int* __restrict__ offs_src,
    int* __restrict__ srcs_s, int* __restrict__ dsts_s,
    const int* __restrict__ erows, const int* __restrict__ ecols,
    const float* __restrict__ evals, const int* __restrict__ re,
    const int* __restrict__ offs_e, int2* __restrict__ ev_e,
    const int* __restrict__ vrows, const int* __restrict__ vcols,
    const float* __restrict__ vvals, const int* __restrict__ rv,
    const int* __restrict__ offs_v, int2* __restrict__ ev_v)
{
    int b = blockIdx.x;
    if (b < GN_) {
        gemm_body(b, vfeat, psi1_W, 2 * D, nullptr, Pv_b, NN, 2);
    } else {
        fill_body(b - GN_, src, dst, rinc_d, rinc_s, offs_dst, offs_src,
                  srcs_s, dsts_s, erows, ecols, evals, re, offs_e, ev_e,
                  vrows, vcols, vvals, rv, offs_v, ev_v);
    }
}

// ---------------- gather bodies (bf16 tables, fp32 accumulate) ------------------------
__device__ __forceinline__ void gatherA_body(int rb,
    const int* __restrict__ offs, const int* __restrict__ srcs,
    const float* __restrict__ invDV, const u16* __restrict__ Pv_b,
    const float* __restrict__ PeP, u16* __restrict__ A_b)
{
    int e = rb * 4 + (threadIdx.x >> 6);
    int l = threadIdx.x & 63;
    if (e >= NE) return;
    int j0 = offs[e], j1 = offs[e + 1];
    float2 acc = make_float2(0.f, 0.f);
    float wsum = 0.f;
    int j = j0;
    for (; j + 3 < j1; j += 4) {
        int s0 = srcs[j], s1 = srcs[j+1], s2 = srcs[j+2], s3 = srcs[j+3];
        float w0 = invDV[s0], w1 = invDV[s1], w2 = invDV[s2], w3 = invDV[s3];
        float2 p0 = ldbf2(Pv_b + (size_t)s0 * D, l);
        float2 p1 = ldbf2(Pv_b + (size_t)s1 * D, l);
        float2 p2 = ldbf2(Pv_b + (size_t)s2 * D, l);
        float2 p3 = ldbf2(Pv_b + (size_t)s3 * D, l);
        wsum += w0 + w1 + w2 + w3;
        acc.x = fmaf(w0, p0.x, fmaf(w1, p1.x, fmaf(w2, p2.x, fmaf(w3, p3.x, acc.x))));
        acc.y = fmaf(w0, p0.y, fmaf(w1, p1.y, fmaf(w2, p2.y, fmaf(w3, p3.y, acc.y))));
    }
    for (; j < j1; ++j) {
        int s = srcs[j];
        float w = invDV[s];
        float2 p = ldbf2(Pv_b + (size_t)s * D, l);
        wsum += w;
        acc.x = fmaf(w, p.x, acc.x);
        acc.y = fmaf(w, p.y, acc.y);
    }
    float2 pe = ((const float2*)(PeP + (size_t)e * D))[l];
    acc.x = fmaf(wsum, pe.x, acc.x);
    acc.y = fmaf(wsum, pe.y, acc.y);
    ushort2 u; u.x = f2bf(acc.x); u.y = f2bf(acc.y);
    ((ushort2*)(A_b + (size_t)e * D))[l] = u;
}

// sum of bf16 rows over a CSR segment -> bf16 out
__device__ __forceinline__ void segsum_bf_body(int rb,
    const int* __restrict__ offs, const int* __restrict__ idx,
    const u16* __restrict__ Tb, u16* __restrict__ Yb, int R)
{
    int r = rb * 4 + (threadIdx.x >> 6);
    int l = threadIdx.x & 63;
    if (r >= R) return;
    int j0 = offs[r], j1 = offs[r + 1];
    float2 acc = make_float2(0.f, 0.f);
    int j = j0;
    for (; j + 3 < j1; j += 4) {
        int d0 = idx[j], d1 = idx[j+1], d2 = idx[j+2], d3 = idx[j+3];
        float2 p0 = ldbf2(Tb + (size_t)d0 * D, l);
        float2 p1 = ldbf2(Tb + (size_t)d1 * D, l);
        float2 p2 = ldbf2(Tb + (size_t)d2 * D, l);
        float2 p3 = ldbf2(Tb + (size_t)d3 * D, l);
        acc.x += (p0.x + p1.x) + (p2.x + p3.x);
        acc.y += (p0.y + p1.y) + (p2.y + p3.y);
    }
    for (; j < j1; ++j) {
        int d = idx[j];
        float2 p = ldbf2(Tb + (size_t)d * D, l);
        acc.x += p.x; acc.y += p.y;
    }
    ushort2 u; u.x = f2bf(acc.x); u.y = f2bf(acc.y);
    ((ushort2*)(Yb + (size_t)r * D))[l] = u;
}

// sum of bf16 rows over a CSR segment -> fp32 out
__device__ __forceinline__ void segsum_f_body(int rb,
    const int* __restrict__ offs, const int* __restrict__ idx,
    const u16* __restrict__ Tb, float* __restrict__ Y, int R)
{
    int r = rb * 4 + (threadIdx.x >> 6);
    int l = threadIdx.x & 63;
    if (r >= R) return;
    int j0 = offs[r], j1 = offs[r + 1];
    float2 acc = make_float2(0.f, 0.f);
    int j = j0;
    for (; j + 3 < j1; j += 4) {
        int d0 = idx[j], d1 = idx[j+1], d2 = idx[j+2], d3 = idx[j+3];
        float2 p0 = ldbf2(Tb + (size_t)d0 * D, l);
        float2 p1 = ldbf2(Tb + (size_t)d1 * D, l);
        float2 p2 = ldbf2(Tb + (size_t)d2 * D, l);
        float2 p3 = ldbf2(Tb + (size_t)d3 * D, l);
        acc.x += (p0.x + p1.x) + (p2.x + p3.x);
        acc.y += (p0.y + p1.y) + (p2.y + p3.y);
    }
    for (; j < j1; ++j) {
        int d = idx[j];
        float2 p = ldbf2(Tb + (size_t)d * D, l);
        acc.x += p.x; acc.y += p.y;
    }
    ((float2*)(Y + (size_t)r * D))[l] = acc;
}

// spmm from bf16 table: Yb[r] = bf16( sum val*Xb[col] + (addend?addend[r]:0) )
__device__ __forceinline__ void spmm_bf_body(int rb,
    const int* __restrict__ offs, const int2* __restrict__ ev,
    const u16* __restrict__ Xb, const float* __restrict__ addend,
    u16* __restrict__ Yb, int R)
{
    int r = rb * 4 + (threadIdx.x >> 6);
    int l = threadIdx.x & 63;
    if (r >= R) return;
    int j0 = offs[r], j1 = offs[r + 1];
    float2 acc = addend ? ((const float2*)(addend + (size_t)r * D))[l]
                        : make_float2(0.f, 0.f);
    int j = j0;
    for (; j + 3 < j1; j += 4) {
        int2 e0 = ev[j], e1 = ev[j+1], e2 = ev[j+2], e3 = ev[j+3];
        float2 x0 = ldbf2(Xb + (size_t)e0.x * D, l);
        float2 x1 = ldbf2(Xb + (size_t)e1.x * D, l);
        float2 x2 = ldbf2(Xb + (size_t)e2.x * D, l);
        float2 x3 = ldbf2(Xb + (size_t)e3.x * D, l);
        float v0 = __int_as_float(e0.y), v1 = __int_as_float(e1.y);
        float v2 = __int_as_float(e2.y), v3 = __int_as_float(e3.y);
        acc.x = fmaf(v0, x0.x, fmaf(v1, x1.x, fmaf(v2, x2.x, fmaf(v3, x3.x, acc.x))));
        acc.y = fmaf(v0, x0.y, fmaf(v1, x1.y, fmaf(v2, x2.y, fmaf(v3, x3.y, acc.y))));
    }
    for (; j < j1; ++j) {
        int2 e = ev[j];
        float2 x = ldbf2(Xb + (size_t)e.x * D, l);
        float v = __int_as_float(e.y);
        acc.x = fmaf(v, x.x, acc.x);
        acc.y = fmaf(v, x.y, acc.y);
    }
    ushort2 u; u.x = f2bf(acc.x); u.y = f2bf(acc.y);
    ((ushort2*)(Yb + (size_t)r * D))[l] = u;
}

// ---------------- fusedA: gather_A | vf2 = segsum(efeat_b over src-CSR) ---------------
__global__ __launch_bounds__(256) void fusedA(
    const int* __restrict__ offs_dst, const int* __restrict__ srcs_s,
    const float* __restrict__ invDV, const u16* __restrict__ Pv_b,
    const float* __restrict__ PeP, u16* __restrict__ A_b,
    const int* __restrict__ offs_src, const int* __restrict__ dsts_s,
    const u16* __restrict__ efeat_b, u16* __restrict__ vf2_b)
{
    int b = blockIdx.x;
    if (b < GER) gatherA_body(b, offs_dst, srcs_s, invDV, Pv_b, PeP, A_b);
    else segsum_bf_body(b - GER, offs_src, dsts_s, efeat_b, vf2_b, NN);
}

// ---------------- fusedB: A2 = emat@A + efeat | vf2b = vmat@vf2 ----------------------
__global__ __launch_bounds__(256) void fusedB(
    const int* __restrict__ offs_e, const int2* __restrict__ ev_e,
    const u16* __restrict__ A_b, const float* __restrict__ efeat, u16* __restrict__ A2_b,
    const int* __restrict__ offs_v, const int2* __restrict__ ev_v,
    const u16* __restrict__ vf2_b, u16* __restrict__ vf2b_b)
{
    int b = blockIdx.x;
    if (b < GER) spmm_bf_body(b, offs_e, ev_e, A_b, efeat, A2_b, NE);
    else spmm_bf_body(b - GER, offs_v, ev_v, vf2_b, nullptr, vf2b_b, NN);
}

// ---------------- vf1 = segsum(A2_b over src-CSR) -> fp32 -----------------------------
__global__ __launch_bounds__(256) void gather_vf1(
    const int* __restrict__ offs_src, const int* __restrict__ dsts_s,
    const u16* __restrict__ A2_b, float* __restrict__ vf1)
{
    segsum_f_body(blockIdx.x, offs_src, dsts_s, A2_b, vf1, NN);
}

// ---------------- fusedC: gemm Wv (relu) | av = segsum(vf2b_b over dst-CSR) -----------
__global__ __launch_bounds__(256) void fusedC(
    const float* __restrict__ vf1, const float* __restrict__ Wv, float* __restrict__ out_v,
    const int* __restrict__ offs_dst, const int* __restrict__ srcs_s,
    const u16* __restrict__ vf2b_b, float* __restrict__ av)
{
    int b = blockIdx.x;
    if (b < GN_) gemm_body(b, vf1, Wv, D, nullptr, out_v, NN, 1);
    else segsum_f_body(b - GN_, offs_dst, srcs_s, vf2b_b, av, NE);
}

// ------- ef2[e] = (sum Qv_b[s] + deg*QeP[e]) * invDE[e] + av[e] -----------------------
__global__ __launch_bounds__(256) void gather_QF(
    const int* __restrict__ offs, const int* __restrict__ srcs,
    const u16* __restrict__ Qv_b, const float* __restrict__ QeP,
    const float* __restrict__ invDE, const float* __restrict__ av,
    float* __restrict__ ef2)
{
    int e = blockIdx.x * 4 + (threadIdx.x >> 6);
    int l = threadIdx.x & 63;
    if (e >= NE) return;
    int j0 = offs[e], j1 = offs[e + 1];
    float deg = (float)(j1 - j0);
    float2 aq = make_float2(0.f, 0.f);
    int j = j0;
    for (; j + 3 < j1; j += 4) {
        int s0 = srcs[j], s1 = srcs[j+1], s2 = srcs[j+2], s3 = srcs[j+3];
        float2 q0 = ldbf2(Qv_b + (size_t)s0 * D, l);
        float2 q1 = ldbf2(Qv_b + (size_t)s1 * D, l);
        float2 q2 = ldbf2(Qv_b + (size_t)s2 * D, l);
        float2 q3 = ldbf2(Qv_b + (size_t)s3 * D, l);
        aq.x += (q0.x + q1.x) + (q2.x + q3.x);
        aq.y += (q0.y + q1.y) + (q2.y + q3.y);
    }
    for (; j < j1; ++j) {
        int s = srcs[j];
        float2 q = ldbf2(Qv_b + (size_t)s * D, l);
        aq.x += q.x; aq.y += q.y;
    }
    float2 qe = ((const float2*)(QeP + (size_t)e * D))[l];
    float2 a  = ((const float2*)(av  + (size_t)e * D))[l];
    float ide = invDE[e];
    float2 o;
    o.x = fmaf(deg, qe.x, aq.x) * ide + a.x;
    o.y = fmaf(deg, qe.y, aq.y) * ide + a.y;
    ((float2*)(ef2 + (size_t)e * D))[l] = o;
}

extern "C" void kernel_launch(void* const* d_in, const int* in_sizes, int n_in,
                              void* d_out, int out_size, void* d_ws, size_t ws_size,
                              hipStream_t stream)
{
    (void)in_sizes; (void)n_in; (void)out_size; (void)ws_size;
    const float* vfeat     = (const float*)d_in[0];
    const float* efeat     = (const float*)d_in[1];
    const float* invDV     = (const float*)d_in[2];
    const float* invDE     = (const float*)d_in[3];
    const int*   inc_src   = (const int*)d_in[4];
    const int*   inc_dst   = (const int*)d_in[5];
    const int*   emat_rows = (const int*)d_in[6];
    const int*   emat_cols = (const int*)d_in[7];
    const float* emat_vals = (const float*)d_in[8];
    const int*   vmat_rows = (const int*)d_in[9];
    const int*   vmat_cols = (const int*)d_in[10];
    const float* vmat_vals = (const float*)d_in[11];
    const float* Wv        = (const float*)d_in[12];
    const float* We        = (const float*)d_in[13];
    const float* psi1_W    = (const float*)d_in[14];
    const float* psi1_b    = (const float*)d_in[15];
    const float* psi2_W    = (const float*)d_in[16];
    const float* psi2_b    = (const float*)d_in[17];

    const size_t ND = (size_t)NN * D;
    const size_t ED = (size_t)NE * D;

    char* p = (char*)d_ws;
    auto alloc = [&](size_t bytes) {
        size_t a = (size_t)p; a = (a + 15) & ~(size_t)15;
        p = (char*)a; void* r = (void*)p; p += bytes; return r;
    };
    float* PeP   = (float*)alloc(ED * 4);
    float* QeP   = (float*)alloc(ED * 4);
    float* vf1   = (float*)alloc(ND * 4);
    float* av    = (float*)alloc(ED * 4);
    float* ef2   = (float*)alloc(ED * 4);
    u16* Pv_b    = (u16*)alloc(ND * 2);
    u16* Qv_b    = (u16*)alloc(ND * 2);
    u16* vf2_b   = (u16*)alloc(ND * 2);
    u16* vf2b_b  = (u16*)alloc(ND * 2);
    u16* A_b     = (u16*)alloc(ED * 2);
    u16* A2_b    = (u16*)alloc(ED * 2);
    u16* efeat_b = (u16*)alloc(ED * 2);
    int* cnt_dst = (int*)alloc((size_t)(2 * NE + 2 * NN) * 4);  // one memset block
    int* cnt_src = cnt_dst + NE;
    int* cnt_e   = cnt_src + NN;
    int* cnt_v   = cnt_e + NE;
    int* offs_dst = (int*)alloc((NE + 1) * 4);
    int* offs_src = (int*)alloc((NN + 1) * 4);
    int* offs_e   = (int*)alloc((NE + 1) * 4);
    int* offs_v   = (int*)alloc((NN + 1) * 4);
    int* rinc_d   = (int*)alloc(NNZ_INC * 4);
    int* rinc_s   = (int*)alloc(NNZ_INC * 4);
    int* re       = (int*)alloc(NNZ_E * 4);
    int* rv       = (int*)alloc(NNZ_V * 4);
    int* srcs_s   = (int*)alloc(NNZ_INC * 4);
    int* dsts_s   = (int*)alloc(NNZ_INC * 4);
    int* bsums    = (int*)alloc(NB_TOT * 4);
    int2* ev_e    = (int2*)alloc((size_t)NNZ_E * 8);
    int2* ev_v    = (int2*)alloc((size_t)NNZ_V * 8);

    float* out_v = (float*)d_out;     // [NN,D]
    float* out_e = out_v + ND;        // [NE,D]

    dim3 b256(256);

    // ---- CSR build phase 1 overlapped with efeat-side gemms ----
    hipMemsetAsync(cnt_dst, 0, (size_t)(2 * NE + 2 * NN) * sizeof(int), stream);
    fused0<<<G_FILL + 2 * GE_ + G_CVT, b256, 0, stream>>>(
        inc_src, inc_dst, cnt_src, cnt_dst, rinc_s, rinc_d,
        emat_rows, cnt_e, re, vmat_rows, cnt_v, rv,
        efeat, psi1_W, psi1_b, PeP, psi2_W, psi2_b, QeP, efeat_b);
    scan_partial<<<NB_TOT, b256, 0, stream>>>(cnt_dst, cnt_src, cnt_e, cnt_v, bsums);
    scan_bsums<<<1, b256, 0, stream>>>(bsums, offs_dst, offs_src, offs_e, offs_v);
    scan_final<<<NB_TOT, b256, 0, stream>>>(cnt_dst, offs_dst, cnt_src, offs_src,
                                            cnt_e, offs_e, cnt_v, offs_v, bsums);
    // ---- fill overlapped with Pv gemm ----
    fusedF<<<GN_ + G_FILL, b256, 0, stream>>>(
        vfeat, psi1_W, Pv_b,
        inc_src, inc_dst, rinc_d, rinc_s, offs_dst, offs_src, srcs_s, dsts_s,
        emat_rows, emat_cols, emat_vals, re, offs_e, ev_e,
        vmat_rows, vmat_cols, vmat_vals, rv, offs_v, ev_v);
    // ---- A | vf2 ----
    fusedA<<<GER + GNR, b256, 0, stream>>>(
        offs_dst, srcs_s, invDV, Pv_b, PeP, A_b,
        offs_src, dsts_s, efeat_b, vf2_b);
    // ---- A2 | vf2b ----
    fusedB<<<GER + GNR, b256, 0, stream>>>(
        offs_e, ev_e, A_b, efeat, A2_b,
        offs_v, ev_v, vf2_b, vf2b_b);
    // ---- vf1 ----
    gather_vf1<<<GNR, b256, 0, stream>>>(offs_src, dsts_s, A2_b, vf1);
    // ---- out_v | av ----
    fusedC<<<GN_ + GER, b256, 0, stream>>>(vf1, Wv, out_v, offs_dst, srcs_s, vf2b_b, av);
    // ---- Qv ----
    gemm128<<<GN_, b256, 0, stream>>>(out_v, psi2_W, 2 * D, nullptr, Qv_b, NN, 2);
    // ---- ef2 ----
    gather_QF<<<GER, b256, 0, stream>>>(offs_dst, srcs_s, Qv_b, QeP, invDE, av, ef2);
    // ---- out_e ----
    gemm128<<<GE_, b256, 0, stream>>>(ef2, We, D, nullptr, out_e, NE, 1);
}